// Round 1
// baseline (1673.057 us; speedup 1.0000x reference)
//
#include <hip/hip_runtime.h>

// SAModule (PointNet++ set-abstraction): FPS -> kNN(32) -> [x||rel] MLP(67->128->128->256) -> max over K.
// B=16, N=4096, C=64, M=1024, K=32.
// d_in: x, pos, W1, b1, W2, b2, W3, b3 (all f32)
// d_out: out[16*1024*256] f32 then pos_s[16*1024*3] f32.

#define B_  16
#define N_  4096
#define M_  1024
#define K_  32

typedef __bf16 bf16x8 __attribute__((ext_vector_type(8)));
typedef __bf16 bf16x4 __attribute__((ext_vector_type(4)));
typedef float  f32x4  __attribute__((ext_vector_type(4)));

// ---------------------------------------------------------------------------
// Weight prep: transpose + cast to bf16, pad W1 K-dim 67->96 with zeros.
// w1t[n][k] (128x96), w2t[n][k] (128x128), w3t[n][k] (256x128)
// ---------------------------------------------------------------------------
__global__ __launch_bounds__(256) void prep_weights(
    const float* __restrict__ W1, const float* __restrict__ W2,
    const float* __restrict__ W3,
    __bf16* __restrict__ w1t, __bf16* __restrict__ w2t, __bf16* __restrict__ w3t) {
  const int t = blockIdx.x * 256 + threadIdx.x;   // 0..32767
  if (t < 128 * 96) {
    const int n = t / 96, k = t % 96;
    w1t[t] = (k < 67) ? (__bf16)W1[k * 128 + n] : (__bf16)0.0f;
  }
  if (t < 128 * 128) {
    const int n = t >> 7, k = t & 127;
    w2t[t] = (__bf16)W2[k * 128 + n];
  }
  {
    const int n = t >> 7, k = t & 127;   // t < 256*128 always
    w3t[t] = (__bf16)W3[k * 256 + n];
  }
}

// ---------------------------------------------------------------------------
// FPS: one block per cloud, 256 threads, 16 points/thread in registers.
// Distances computed with _rn ops in ((dx^2+dy^2)+dz^2) order to match the
// numpy/XLA reference bit-exactly; argmax ties -> lowest index (first occurrence).
// ---------------------------------------------------------------------------
__global__ __launch_bounds__(256) void fps_kernel(const float* __restrict__ pos,
                                                  int* __restrict__ fps_idx,
                                                  float* __restrict__ pos_s) {
  __shared__ alignas(16) float4 pp[N_];
  __shared__ alignas(16) float  swv[2][4];
  __shared__ alignas(16) int    swi[2][4];

  const int b   = blockIdx.x;
  const int tid = threadIdx.x;
  const float* pb = pos + (size_t)b * N_ * 3;
  for (int i = tid; i < N_; i += 256)
    pp[i] = make_float4(pb[3 * i], pb[3 * i + 1], pb[3 * i + 2], 0.0f);
  __syncthreads();

  float X[16], Y[16], Z[16], D[16];
#pragma unroll
  for (int k = 0; k < 16; k++) {
    float4 p = pp[tid + (k << 8)];
    X[k] = p.x; Y[k] = p.y; Z[k] = p.z; D[k] = 1e30f;
  }

  int cur = 0;
  if (tid == 0) {
    fps_idx[b * M_] = 0;
    float4 p = pp[0];
    float* o = pos_s + (size_t)b * M_ * 3;
    o[0] = p.x; o[1] = p.y; o[2] = p.z;
  }
  const int wid  = tid >> 6;
  const int lane = tid & 63;

  for (int i = 1; i < M_; i++) {
    const float4 q = pp[cur];
    float bv = -1.0f; int bi = 0;
#pragma unroll
    for (int k = 0; k < 16; k++) {
      float dx = __fsub_rn(X[k], q.x);
      float dy = __fsub_rn(Y[k], q.y);
      float dz = __fsub_rn(Z[k], q.z);
      float d  = __fadd_rn(__fadd_rn(__fmul_rn(dx, dx), __fmul_rn(dy, dy)),
                           __fmul_rn(dz, dz));
      D[k] = fminf(D[k], d);
      if (D[k] > bv) { bv = D[k]; bi = tid + (k << 8); }  // k asc => idx asc => first-max kept
    }
#pragma unroll
    for (int off = 1; off < 64; off <<= 1) {
      float ov = __shfl_xor(bv, off);
      int   oi = __shfl_xor(bi, off);
      if (ov > bv || (ov == bv && oi < bi)) { bv = ov; bi = oi; }
    }
    const int par = i & 1;
    if (lane == 0) { swv[par][wid] = bv; swi[par][wid] = bi; }
    __syncthreads();
    const float4 vv = *(const float4*)&swv[par][0];
    const int4   ii = *(const int4*)&swi[par][0];
    float v = vv.x; int id = ii.x;
    if (vv.y > v || (vv.y == v && ii.y < id)) { v = vv.y; id = ii.y; }
    if (vv.z > v || (vv.z == v && ii.z < id)) { v = vv.z; id = ii.z; }
    if (vv.w > v || (vv.w == v && ii.w < id)) { v = vv.w; id = ii.w; }
    cur = id;
    if (tid == 0) {
      fps_idx[b * M_ + i] = cur;
      float4 p = pp[cur];
      float* o = pos_s + ((size_t)b * M_ + i) * 3;
      o[0] = p.x; o[1] = p.y; o[2] = p.z;
    }
  }
}

// ---------------------------------------------------------------------------
// kNN: one wave per centroid (4 waves/block share staged cloud in LDS).
// Lanes 0..31 hold the current 32 best keys, sorted ascending.
// key = (f32bits(d2) << 32) | idx  -> lexicographic (d2, idx), exactly matching
// top_k tie semantics (strictly-smaller key evicts the lane-31 max key).
// ---------------------------------------------------------------------------
__global__ __launch_bounds__(256) void knn_kernel(const float* __restrict__ pos,
                                                  const int* __restrict__ fps_idx,
                                                  unsigned short* __restrict__ nbr) {
  __shared__ alignas(16) float4 pp[N_];
  const int b    = blockIdx.x >> 8;
  const int mset = blockIdx.x & 255;
  const int tid  = threadIdx.x;
  const int w    = tid >> 6;
  const int lane = tid & 63;

  const float* pb = pos + (size_t)b * N_ * 3;
  for (int i = tid; i < N_; i += 256)
    pp[i] = make_float4(pb[3 * i], pb[3 * i + 1], pb[3 * i + 2], 0.0f);
  __syncthreads();

  const int m  = mset * 4 + w;
  const int ci = fps_idx[b * M_ + m];
  const float4 c = pp[ci];

  unsigned long long rkey = ~0ull;   // lanes >=32 stay at MAX forever

  for (int t = 0; t < N_ / 64; t++) {
    const int j = t * 64 + lane;
    const float4 p = pp[j];
    float dx = __fsub_rn(p.x, c.x);
    float dy = __fsub_rn(p.y, c.y);
    float dz = __fsub_rn(p.z, c.z);
    float d  = __fadd_rn(__fadd_rn(__fmul_rn(dx, dx), __fmul_rn(dy, dy)),
                         __fmul_rn(dz, dz));
    const unsigned long long k64 =
        ((unsigned long long)__float_as_uint(d) << 32) | (unsigned int)j;

    unsigned long long wk = __shfl(rkey, 31);
    unsigned long long mask = __ballot(k64 < wk);
    while (mask) {
      const int src = __ffsll((unsigned long long)mask) - 1;
      mask &= mask - 1;
      const unsigned long long cand = __shfl(k64, src);
      wk = __shfl(rkey, 31);                    // refresh current worst
      if (cand < wk) {                          // wave-uniform branch
        const int pos_i = (int)__popcll(__ballot(rkey < cand));
        const unsigned long long sh = __shfl_up(rkey, 1);
        if (lane < 32) {
          if (lane == pos_i)      rkey = cand;
          else if (lane > pos_i)  rkey = sh;
        }
      }
    }
  }
  if (lane < 32)
    nbr[(size_t)(b * M_ + m) * K_ + lane] = (unsigned short)(rkey & 0xFFFFull);
}

// ---------------------------------------------------------------------------
// Fused gather + MLP + maxpool. Block = 4 waves = 4 centroids (128 rows).
// Wave w owns rows [32w, 32w+32) = the 32 neighbors of its centroid; each wave
// runs gather -> L1 -> L2 -> L3 -> maxpool on its own rows.
// LDS activation stride 136 bf16 (16B-aligned rows, spreads banks).
// MFMA 16x16x32 bf16: A lane: row=l&15, k=8*(l>>4)+i ; B lane: col=l&15, same k;
// D lane: col=l&15, row=4*(l>>4)+j  [verified mapping].
// ---------------------------------------------------------------------------
#define AST 136

__global__ __launch_bounds__(256) void mlp_kernel(
    const float* __restrict__ x, const float* __restrict__ pos,
    const float* __restrict__ b1, const float* __restrict__ b2,
    const float* __restrict__ b3,
    const unsigned short* __restrict__ nbr,
    const __bf16* __restrict__ w1t, const __bf16* __restrict__ w2t,
    const __bf16* __restrict__ w3t,
    float* __restrict__ out, const float* __restrict__ pos_s) {
  __shared__ alignas(16) __bf16 bufA[128 * AST];   // msg (k=0..95), later act2 (k=0..127)
  __shared__ alignas(16) __bf16 bufB[128 * AST];   // act1

  const int b    = blockIdx.x >> 8;
  const int mset = blockIdx.x & 255;
  const int w    = threadIdx.x >> 6;
  const int lane = threadIdx.x & 63;
  const int m    = mset * 4 + w;

  // ---- gather: 2 lanes per row ----
  {
    const int rl   = lane >> 1;      // neighbor slot 0..31
    const int half = lane & 1;
    const int r    = w * 32 + rl;
    const int nj   = (int)nbr[(size_t)(b * M_ + m) * K_ + rl];
    const float4* xr = (const float4*)(x + ((size_t)(b * N_ + nj)) * 64 + half * 32);
    __bf16* dst = &bufA[r * AST + half * 32];
#pragma unroll
    for (int t = 0; t < 8; t++) {
      float4 v = xr[t];
      bf16x4 u;
      u[0] = (__bf16)v.x; u[1] = (__bf16)v.y; u[2] = (__bf16)v.z; u[3] = (__bf16)v.w;
      *(bf16x4*)(dst + t * 4) = u;
    }
    bf16x8 z;
#pragma unroll
    for (int q2 = 0; q2 < 8; q2++) z[q2] = (__bf16)0.0f;
    if (half == 0) {
      const float* pj = pos + ((size_t)(b * N_ + nj)) * 3;
      const float* ps = pos_s + ((size_t)(b * M_ + m)) * 3;
      bf16x8 u = z;
      u[0] = (__bf16)(pj[0] - ps[0]);
      u[1] = (__bf16)(pj[1] - ps[1]);
      u[2] = (__bf16)(pj[2] - ps[2]);
      *(bf16x8*)&bufA[r * AST + 64] = u;
      *(bf16x8*)&bufA[r * AST + 72] = z;
    } else {
      *(bf16x8*)&bufA[r * AST + 80] = z;
      *(bf16x8*)&bufA[r * AST + 88] = z;
    }
  }
  __syncthreads();

  const int lrow  = lane & 15;
  const int lk8   = (lane >> 4) << 3;   // k offset within 32-step
  const int orow  = (lane >> 4) << 2;   // D row base within tile
  const int rbase = w * 32;

  // ---- layer 1: msg(96) @ W1 -> relu -> bufB(128) ----
  {
    f32x4 acc0[8], acc1[8];
#pragma unroll
    for (int n = 0; n < 8; n++) {
      const float bv = b1[n * 16 + lrow];
      f32x4 a = {bv, bv, bv, bv};
      acc0[n] = a; acc1[n] = a;
    }
#pragma unroll
    for (int s = 0; s < 3; s++) {
      bf16x8 a0 = *(const bf16x8*)&bufA[(rbase + lrow) * AST + s * 32 + lk8];
      bf16x8 a1 = *(const bf16x8*)&bufA[(rbase + 16 + lrow) * AST + s * 32 + lk8];
#pragma unroll
      for (int n = 0; n < 8; n++) {
        bf16x8 bb = *(const bf16x8*)&w1t[(n * 16 + lrow) * 96 + s * 32 + lk8];
        acc0[n] = __builtin_amdgcn_mfma_f32_16x16x32_bf16(a0, bb, acc0[n], 0, 0, 0);
        acc1[n] = __builtin_amdgcn_mfma_f32_16x16x32_bf16(a1, bb, acc1[n], 0, 0, 0);
      }
    }
#pragma unroll
    for (int n = 0; n < 8; n++)
#pragma unroll
      for (int j = 0; j < 4; j++) {
        bufB[(rbase + orow + j) * AST + n * 16 + lrow]      = (__bf16)fmaxf(acc0[n][j], 0.0f);
        bufB[(rbase + 16 + orow + j) * AST + n * 16 + lrow] = (__bf16)fmaxf(acc1[n][j], 0.0f);
      }
  }
  __syncthreads();

  // ---- layer 2: bufB(128) @ W2 -> relu -> bufA(128) ----
  {
    f32x4 acc0[8], acc1[8];
#pragma unroll
    for (int n = 0; n < 8; n++) {
      const float bv = b2[n * 16 + lrow];
      f32x4 a = {bv, bv, bv, bv};
      acc0[n] = a; acc1[n] = a;
    }
#pragma unroll
    for (int s = 0; s < 4; s++) {
      bf16x8 a0 = *(const bf16x8*)&bufB[(rbase + lrow) * AST + s * 32 + lk8];
      bf16x8 a1 = *(const bf16x8*)&bufB[(rbase + 16 + lrow) * AST + s * 32 + lk8];
#pragma unroll
      for (int n = 0; n < 8; n++) {
        bf16x8 bb = *(const bf16x8*)&w2t[(n * 16 + lrow) * 128 + s * 32 + lk8];
        acc0[n] = __builtin_amdgcn_mfma_f32_16x16x32_bf16(a0, bb, acc0[n], 0, 0, 0);
        acc1[n] = __builtin_amdgcn_mfma_f32_16x16x32_bf16(a1, bb, acc1[n], 0, 0, 0);
      }
    }
#pragma unroll
    for (int n = 0; n < 8; n++)
#pragma unroll
      for (int j = 0; j < 4; j++) {
        bufA[(rbase + orow + j) * AST + n * 16 + lrow]      = (__bf16)fmaxf(acc0[n][j], 0.0f);
        bufA[(rbase + 16 + orow + j) * AST + n * 16 + lrow] = (__bf16)fmaxf(acc1[n][j], 0.0f);
      }
  }
  __syncthreads();

  // ---- layer 3 (two 128-col halves) + maxpool over the wave's 32 rows ----
  for (int nh = 0; nh < 2; nh++) {
    f32x4 acc0[8], acc1[8];
#pragma unroll
    for (int n = 0; n < 8; n++) {
      const float bv = b3[nh * 128 + n * 16 + lrow];
      f32x4 a = {bv, bv, bv, bv};
      acc0[n] = a; acc1[n] = a;
    }
#pragma unroll
    for (int s = 0; s < 4; s++) {
      bf16x8 a0 = *(const bf16x8*)&bufA[(rbase + lrow) * AST + s * 32 + lk8];
      bf16x8 a1 = *(const bf16x8*)&bufA[(rbase + 16 + lrow) * AST + s * 32 + lk8];
#pragma unroll
      for (int n = 0; n < 8; n++) {
        bf16x8 bb = *(const bf16x8*)&w3t[(nh * 128 + n * 16 + lrow) * 128 + s * 32 + lk8];
        acc0[n] = __builtin_amdgcn_mfma_f32_16x16x32_bf16(a0, bb, acc0[n], 0, 0, 0);
        acc1[n] = __builtin_amdgcn_mfma_f32_16x16x32_bf16(a1, bb, acc1[n], 0, 0, 0);
      }
    }
#pragma unroll
    for (int n = 0; n < 8; n++) {
      float v = fmaxf(fmaxf(fmaxf(acc0[n][0], acc0[n][1]), fmaxf(acc0[n][2], acc0[n][3])),
                      fmaxf(fmaxf(acc1[n][0], acc1[n][1]), fmaxf(acc1[n][2], acc1[n][3])));
      v = fmaxf(v, __shfl_xor(v, 16));
      v = fmaxf(v, __shfl_xor(v, 32));
      v = fmaxf(v, 0.0f);   // relu commutes with max
      if (lane < 16)
        out[((size_t)(b * M_ + m)) * 256 + nh * 128 + n * 16 + lane] = v;
    }
  }
}

// ---------------------------------------------------------------------------
extern "C" void kernel_launch(void* const* d_in, const int* in_sizes, int n_in,
                              void* d_out, int out_size, void* d_ws, size_t ws_size,
                              hipStream_t stream) {
  const float* x   = (const float*)d_in[0];
  const float* pos = (const float*)d_in[1];
  const float* W1  = (const float*)d_in[2];
  const float* b1  = (const float*)d_in[3];
  const float* W2  = (const float*)d_in[4];
  const float* b2  = (const float*)d_in[5];
  const float* W3  = (const float*)d_in[6];
  const float* b3  = (const float*)d_in[7];

  float* out   = (float*)d_out;
  float* pos_s = out + (size_t)B_ * M_ * 256;

  char* ws = (char*)d_ws;
  int*            fps_idx = (int*)ws;                              // 65536 B
  unsigned short* nbr     = (unsigned short*)(ws + 65536);         // 1048576 B
  __bf16*         w1t     = (__bf16*)(ws + 1114112);               // 24576 B
  __bf16*         w2t     = (__bf16*)(ws + 1138688);               // 32768 B
  __bf16*         w3t     = (__bf16*)(ws + 1171456);               // 65536 B

  prep_weights<<<dim3(128), dim3(256), 0, stream>>>(W1, W2, W3, w1t, w2t, w3t);
  fps_kernel<<<dim3(B_), dim3(256), 0, stream>>>(pos, fps_idx, pos_s);
  knn_kernel<<<dim3(B_ * (M_ / 4)), dim3(256), 0, stream>>>(pos, fps_idx, nbr);
  mlp_kernel<<<dim3(B_ * (M_ / 4)), dim3(256), 0, stream>>>(
      x, pos, b1, b2, b3, nbr, w1t, w2t, w3t, out, pos_s);
}

// Round 2
// 1167.756 us; speedup vs baseline: 1.4327x; 1.4327x over previous
//
#include <hip/hip_runtime.h>

// SAModule (PointNet++ set-abstraction): FPS -> kNN(32) -> [x||rel] MLP(67->128->128->256) -> max over K.
// B=16, N=4096, C=64, M=1024, K=32.
// d_in: x, pos, W1, b1, W2, b2, W3, b3 (all f32)
// d_out: out[16*1024*256] f32 then pos_s[16*1024*3] f32.

#define B_  16
#define N_  4096
#define M_  1024
#define K_  32

typedef __bf16 bf16x8 __attribute__((ext_vector_type(8)));
typedef __bf16 bf16x4 __attribute__((ext_vector_type(4)));
typedef float  f32x4  __attribute__((ext_vector_type(4)));

// ---------------------------------------------------------------------------
// Weight prep: transpose + cast to bf16, pad W1 K-dim 67->96 with zeros.
// ---------------------------------------------------------------------------
__global__ __launch_bounds__(256) void prep_weights(
    const float* __restrict__ W1, const float* __restrict__ W2,
    const float* __restrict__ W3,
    __bf16* __restrict__ w1t, __bf16* __restrict__ w2t, __bf16* __restrict__ w3t) {
  const int t = blockIdx.x * 256 + threadIdx.x;   // 0..32767
  if (t < 128 * 96) {
    const int n = t / 96, k = t % 96;
    w1t[t] = (k < 67) ? (__bf16)W1[k * 128 + n] : (__bf16)0.0f;
  }
  if (t < 128 * 128) {
    const int n = t >> 7, k = t & 127;
    w2t[t] = (__bf16)W2[k * 128 + n];
  }
  {
    const int n = t >> 7, k = t & 127;   // t < 256*128 always
    w3t[t] = (__bf16)W3[k * 256 + n];
  }
}

// ---------------------------------------------------------------------------
// FPS. One block per cloud, 256 threads, 16 points/thread in registers.
// Argmax via u64 key = (f32bits(D) << 32) | ~idx; max-key == (max D, tie->min idx),
// identical to jnp.argmax first-occurrence semantics (D >= 0 so f32 bits are
// monotonic). In-wave reduce on the VALU pipe via DPP (quad_perm/mirrors) +
// one ds_swizzle xor16; cross-wave via 8 LDS partials (parity double-buffered,
// single barrier per iteration).
// Distances use _rn ops in ((dx^2+dy^2)+dz^2) order -> bit-exact vs numpy.
// ---------------------------------------------------------------------------
template <int CTRL>
__device__ __forceinline__ unsigned long long dpp_max_u64(unsigned long long k) {
  unsigned lo = (unsigned)__builtin_amdgcn_update_dpp(0, (int)(unsigned)k,         CTRL, 0xF, 0xF, true);
  unsigned hi = (unsigned)__builtin_amdgcn_update_dpp(0, (int)(unsigned)(k >> 32), CTRL, 0xF, 0xF, true);
  unsigned long long p = ((unsigned long long)hi << 32) | lo;
  return p > k ? p : k;
}

__global__ __launch_bounds__(256) void fps_kernel(const float* __restrict__ pos,
                                                  int* __restrict__ fps_idx,
                                                  float* __restrict__ pos_s) {
  __shared__ alignas(16) float4 pp[N_];
  __shared__ alignas(16) unsigned long long sw[2][8];

  const int b   = blockIdx.x;
  const int tid = threadIdx.x;
  const float* pb = pos + (size_t)b * N_ * 3;
  for (int i = tid; i < N_; i += 256)
    pp[i] = make_float4(pb[3 * i], pb[3 * i + 1], pb[3 * i + 2], 0.0f);
  __syncthreads();

  float X[16], Y[16], Z[16], D[16];
#pragma unroll
  for (int k = 0; k < 16; k++) {
    float4 p = pp[tid + (k << 8)];
    X[k] = p.x; Y[k] = p.y; Z[k] = p.z; D[k] = 1e30f;
  }

  int cur = 0;
  if (tid == 0) {
    fps_idx[b * M_] = 0;
    float4 p = pp[0];
    float* o = pos_s + (size_t)b * M_ * 3;
    o[0] = p.x; o[1] = p.y; o[2] = p.z;
  }
  const unsigned ntid = ~(unsigned)tid;   // ~(tid + (k<<8)) == ntid - (k<<8)

  for (int i = 1; i < M_; i++) {
    const float4 q = pp[cur];
    unsigned long long key[16];
#pragma unroll
    for (int k = 0; k < 16; k++) {
      float dx = __fsub_rn(X[k], q.x);
      float dy = __fsub_rn(Y[k], q.y);
      float dz = __fsub_rn(Z[k], q.z);
      float d  = __fadd_rn(__fadd_rn(__fmul_rn(dx, dx), __fmul_rn(dy, dy)),
                           __fmul_rn(dz, dz));
      D[k] = fminf(D[k], d);
      key[k] = ((unsigned long long)__float_as_uint(D[k]) << 32) |
               (unsigned)(ntid - (unsigned)(k << 8));
    }
    // per-thread tree reduce (depth 4, keeps first-occurrence tie-break via key)
#pragma unroll
    for (int s = 8; s > 0; s >>= 1)
#pragma unroll
      for (int k = 0; k < s; k++)
        if (key[k + s] > key[k]) key[k] = key[k + s];
    unsigned long long kk = key[0];

    // in-wave butterfly, VALU-pipe DPP: xor1, xor2, mirror8, mirror16
    kk = dpp_max_u64<0xB1>(kk);    // quad_perm [1,0,3,2]
    kk = dpp_max_u64<0x4E>(kk);    // quad_perm [2,3,0,1]
    kk = dpp_max_u64<0x141>(kk);   // row_half_mirror
    kk = dpp_max_u64<0x140>(kk);   // row_mirror
    // xor16 within 32-lane group (single LDS-pipe level)
    {
      unsigned lo = (unsigned)__builtin_amdgcn_ds_swizzle((int)(unsigned)kk, 0x401F);
      unsigned hi = (unsigned)__builtin_amdgcn_ds_swizzle((int)(unsigned)(kk >> 32), 0x401F);
      unsigned long long p = ((unsigned long long)hi << 32) | lo;
      if (p > kk) kk = p;
    }
    // now every 32-lane half holds its half-max; 8 partials per block
    const int par = i & 1;
    if ((tid & 31) == 0) sw[par][tid >> 5] = kk;
    __syncthreads();
    const unsigned long long* s8 = sw[par];
    unsigned long long best = s8[0];
#pragma unroll
    for (int j = 1; j < 8; j++) {
      unsigned long long t = s8[j];
      if (t > best) best = t;
    }
    cur = (int)(~(unsigned)best);
    if (tid == 0) {
      fps_idx[b * M_ + i] = cur;
      float4 p = pp[cur];
      float* o = pos_s + ((size_t)b * M_ + i) * 3;
      o[0] = p.x; o[1] = p.y; o[2] = p.z;
    }
  }
}

// ---------------------------------------------------------------------------
// kNN: one wave per centroid (4 waves/block share staged cloud in LDS).
// Lanes 0..31 hold the current 32 best keys, sorted ascending.
// key = (f32bits(d2) << 32) | idx  -> lexicographic (d2, idx) == top_k order.
// Insertion of a non-qualifying candidate is a provable no-op (pos_i >= 32),
// so the tile-start threshold needs no per-candidate refresh.
// ---------------------------------------------------------------------------
__global__ __launch_bounds__(256) void knn_kernel(const float* __restrict__ pos,
                                                  const int* __restrict__ fps_idx,
                                                  unsigned short* __restrict__ nbr) {
  __shared__ alignas(16) float4 pp[N_];
  const int b    = blockIdx.x >> 8;
  const int mset = blockIdx.x & 255;
  const int tid  = threadIdx.x;
  const int w    = tid >> 6;
  const int lane = tid & 63;

  const float* pb = pos + (size_t)b * N_ * 3;
  for (int i = tid; i < N_; i += 256)
    pp[i] = make_float4(pb[3 * i], pb[3 * i + 1], pb[3 * i + 2], 0.0f);
  __syncthreads();

  const int m  = mset * 4 + w;
  const int ci = fps_idx[b * M_ + m];
  const float4 c = pp[ci];

  unsigned long long rkey = ~0ull;   // lanes >=32 stay at MAX forever

  for (int t = 0; t < N_ / 64; t++) {
    const int j = t * 64 + lane;
    const float4 p = pp[j];
    float dx = __fsub_rn(p.x, c.x);
    float dy = __fsub_rn(p.y, c.y);
    float dz = __fsub_rn(p.z, c.z);
    float d  = __fadd_rn(__fadd_rn(__fmul_rn(dx, dx), __fmul_rn(dy, dy)),
                         __fmul_rn(dz, dz));
    const unsigned long long k64 =
        ((unsigned long long)__float_as_uint(d) << 32) | (unsigned int)j;

    const unsigned long long wk = __shfl(rkey, 31);   // tile-start threshold
    unsigned long long mask = __ballot(k64 < wk);
    while (mask) {
      const int src = __ffsll((unsigned long long)mask) - 1;
      mask &= mask - 1;
      const unsigned long long cand = __shfl(k64, src);
      const int pos_i = (int)__popcll(__ballot(rkey < cand));  // >=32 -> no-op
      const unsigned long long sh = __shfl_up(rkey, 1);
      if (lane < 32) {
        if (lane == pos_i)      rkey = cand;
        else if (lane > pos_i)  rkey = sh;
      }
    }
  }
  if (lane < 32)
    nbr[(size_t)(b * M_ + m) * K_ + lane] = (unsigned short)(rkey & 0xFFFFull);
}

// ---------------------------------------------------------------------------
// Fused gather + MLP + maxpool. Block = 4 waves = 4 centroids (128 rows).
// ---------------------------------------------------------------------------
#define AST 136

__global__ __launch_bounds__(256) void mlp_kernel(
    const float* __restrict__ x, const float* __restrict__ pos,
    const float* __restrict__ b1, const float* __restrict__ b2,
    const float* __restrict__ b3,
    const unsigned short* __restrict__ nbr,
    const __bf16* __restrict__ w1t, const __bf16* __restrict__ w2t,
    const __bf16* __restrict__ w3t,
    float* __restrict__ out, const float* __restrict__ pos_s) {
  __shared__ alignas(16) __bf16 bufA[128 * AST];   // msg (k=0..95), later act2 (k=0..127)
  __shared__ alignas(16) __bf16 bufB[128 * AST];   // act1

  const int b    = blockIdx.x >> 8;
  const int mset = blockIdx.x & 255;
  const int w    = threadIdx.x >> 6;
  const int lane = threadIdx.x & 63;
  const int m    = mset * 4 + w;

  // ---- gather: 2 lanes per row ----
  {
    const int rl   = lane >> 1;      // neighbor slot 0..31
    const int half = lane & 1;
    const int r    = w * 32 + rl;
    const int nj   = (int)nbr[(size_t)(b * M_ + m) * K_ + rl];
    const float4* xr = (const float4*)(x + ((size_t)(b * N_ + nj)) * 64 + half * 32);
    __bf16* dst = &bufA[r * AST + half * 32];
#pragma unroll
    for (int t = 0; t < 8; t++) {
      float4 v = xr[t];
      bf16x4 u;
      u[0] = (__bf16)v.x; u[1] = (__bf16)v.y; u[2] = (__bf16)v.z; u[3] = (__bf16)v.w;
      *(bf16x4*)(dst + t * 4) = u;
    }
    bf16x8 z;
#pragma unroll
    for (int q2 = 0; q2 < 8; q2++) z[q2] = (__bf16)0.0f;
    if (half == 0) {
      const float* pj = pos + ((size_t)(b * N_ + nj)) * 3;
      const float* ps = pos_s + ((size_t)(b * M_ + m)) * 3;
      bf16x8 u = z;
      u[0] = (__bf16)(pj[0] - ps[0]);
      u[1] = (__bf16)(pj[1] - ps[1]);
      u[2] = (__bf16)(pj[2] - ps[2]);
      *(bf16x8*)&bufA[r * AST + 64] = u;
      *(bf16x8*)&bufA[r * AST + 72] = z;
    } else {
      *(bf16x8*)&bufA[r * AST + 80] = z;
      *(bf16x8*)&bufA[r * AST + 88] = z;
    }
  }
  __syncthreads();

  const int lrow  = lane & 15;
  const int lk8   = (lane >> 4) << 3;   // k offset within 32-step
  const int orow  = (lane >> 4) << 2;   // D row base within tile
  const int rbase = w * 32;

  // ---- layer 1: msg(96) @ W1 -> relu -> bufB(128) ----
  {
    f32x4 acc0[8], acc1[8];
#pragma unroll
    for (int n = 0; n < 8; n++) {
      const float bv = b1[n * 16 + lrow];
      f32x4 a = {bv, bv, bv, bv};
      acc0[n] = a; acc1[n] = a;
    }
#pragma unroll
    for (int s = 0; s < 3; s++) {
      bf16x8 a0 = *(const bf16x8*)&bufA[(rbase + lrow) * AST + s * 32 + lk8];
      bf16x8 a1 = *(const bf16x8*)&bufA[(rbase + 16 + lrow) * AST + s * 32 + lk8];
#pragma unroll
      for (int n = 0; n < 8; n++) {
        bf16x8 bb = *(const bf16x8*)&w1t[(n * 16 + lrow) * 96 + s * 32 + lk8];
        acc0[n] = __builtin_amdgcn_mfma_f32_16x16x32_bf16(a0, bb, acc0[n], 0, 0, 0);
        acc1[n] = __builtin_amdgcn_mfma_f32_16x16x32_bf16(a1, bb, acc1[n], 0, 0, 0);
      }
    }
#pragma unroll
    for (int n = 0; n < 8; n++)
#pragma unroll
      for (int j = 0; j < 4; j++) {
        bufB[(rbase + orow + j) * AST + n * 16 + lrow]      = (__bf16)fmaxf(acc0[n][j], 0.0f);
        bufB[(rbase + 16 + orow + j) * AST + n * 16 + lrow] = (__bf16)fmaxf(acc1[n][j], 0.0f);
      }
  }
  __syncthreads();

  // ---- layer 2: bufB(128) @ W2 -> relu -> bufA(128) ----
  {
    f32x4 acc0[8], acc1[8];
#pragma unroll
    for (int n = 0; n < 8; n++) {
      const float bv = b2[n * 16 + lrow];
      f32x4 a = {bv, bv, bv, bv};
      acc0[n] = a; acc1[n] = a;
    }
#pragma unroll
    for (int s = 0; s < 4; s++) {
      bf16x8 a0 = *(const bf16x8*)&bufB[(rbase + lrow) * AST + s * 32 + lk8];
      bf16x8 a1 = *(const bf16x8*)&bufB[(rbase + 16 + lrow) * AST + s * 32 + lk8];
#pragma unroll
      for (int n = 0; n < 8; n++) {
        bf16x8 bb = *(const bf16x8*)&w2t[(n * 16 + lrow) * 128 + s * 32 + lk8];
        acc0[n] = __builtin_amdgcn_mfma_f32_16x16x32_bf16(a0, bb, acc0[n], 0, 0, 0);
        acc1[n] = __builtin_amdgcn_mfma_f32_16x16x32_bf16(a1, bb, acc1[n], 0, 0, 0);
      }
    }
#pragma unroll
    for (int n = 0; n < 8; n++)
#pragma unroll
      for (int j = 0; j < 4; j++) {
        bufA[(rbase + orow + j) * AST + n * 16 + lrow]      = (__bf16)fmaxf(acc0[n][j], 0.0f);
        bufA[(rbase + 16 + orow + j) * AST + n * 16 + lrow] = (__bf16)fmaxf(acc1[n][j], 0.0f);
      }
  }
  __syncthreads();

  // ---- layer 3 (two 128-col halves) + maxpool over the wave's 32 rows ----
  for (int nh = 0; nh < 2; nh++) {
    f32x4 acc0[8], acc1[8];
#pragma unroll
    for (int n = 0; n < 8; n++) {
      const float bv = b3[nh * 128 + n * 16 + lrow];
      f32x4 a = {bv, bv, bv, bv};
      acc0[n] = a; acc1[n] = a;
    }
#pragma unroll
    for (int s = 0; s < 4; s++) {
      bf16x8 a0 = *(const bf16x8*)&bufA[(rbase + lrow) * AST + s * 32 + lk8];
      bf16x8 a1 = *(const bf16x8*)&bufA[(rbase + 16 + lrow) * AST + s * 32 + lk8];
#pragma unroll
      for (int n = 0; n < 8; n++) {
        bf16x8 bb = *(const bf16x8*)&w3t[(nh * 128 + n * 16 + lrow) * 128 + s * 32 + lk8];
        acc0[n] = __builtin_amdgcn_mfma_f32_16x16x32_bf16(a0, bb, acc0[n], 0, 0, 0);
        acc1[n] = __builtin_amdgcn_mfma_f32_16x16x32_bf16(a1, bb, acc1[n], 0, 0, 0);
      }
    }
#pragma unroll
    for (int n = 0; n < 8; n++) {
      float v = fmaxf(fmaxf(fmaxf(acc0[n][0], acc0[n][1]), fmaxf(acc0[n][2], acc0[n][3])),
                      fmaxf(fmaxf(acc1[n][0], acc1[n][1]), fmaxf(acc1[n][2], acc1[n][3])));
      v = fmaxf(v, __shfl_xor(v, 16));
      v = fmaxf(v, __shfl_xor(v, 32));
      v = fmaxf(v, 0.0f);   // relu commutes with max
      if (lane < 16)
        out[((size_t)(b * M_ + m)) * 256 + nh * 128 + n * 16 + lane] = v;
    }
  }
}

// ---------------------------------------------------------------------------
extern "C" void kernel_launch(void* const* d_in, const int* in_sizes, int n_in,
                              void* d_out, int out_size, void* d_ws, size_t ws_size,
                              hipStream_t stream) {
  const float* x   = (const float*)d_in[0];
  const float* pos = (const float*)d_in[1];
  const float* W1  = (const float*)d_in[2];
  const float* b1  = (const float*)d_in[3];
  const float* W2  = (const float*)d_in[4];
  const float* b2  = (const float*)d_in[5];
  const float* W3  = (const float*)d_in[6];
  const float* b3  = (const float*)d_in[7];

  float* out   = (float*)d_out;
  float* pos_s = out + (size_t)B_ * M_ * 256;

  char* ws = (char*)d_ws;
  int*            fps_idx = (int*)ws;                              // 65536 B
  unsigned short* nbr     = (unsigned short*)(ws + 65536);         // 1048576 B
  __bf16*         w1t     = (__bf16*)(ws + 1114112);               // 24576 B
  __bf16*         w2t     = (__bf16*)(ws + 1138688);               // 32768 B
  __bf16*         w3t     = (__bf16*)(ws + 1171456);               // 65536 B

  prep_weights<<<dim3(128), dim3(256), 0, stream>>>(W1, W2, W3, w1t, w2t, w3t);
  fps_kernel<<<dim3(B_), dim3(256), 0, stream>>>(pos, fps_idx, pos_s);
  knn_kernel<<<dim3(B_ * (M_ / 4)), dim3(256), 0, stream>>>(pos, fps_idx, nbr);
  mlp_kernel<<<dim3(B_ * (M_ / 4)), dim3(256), 0, stream>>>(
      x, pos, b1, b2, b3, nbr, w1t, w2t, w3t, out, pos_s);
}

// Round 3
// 1093.821 us; speedup vs baseline: 1.5296x; 1.0676x over previous
//
#include <hip/hip_runtime.h>

// SAModule (PointNet++ set-abstraction): FPS -> kNN(32) -> [x||rel] MLP(67->128->128->256) -> max over K.
// B=16, N=4096, C=64, M=1024, K=32.
// d_in: x, pos, W1, b1, W2, b2, W3, b3 (all f32)
// d_out: out[16*1024*256] f32 then pos_s[16*1024*3] f32.

#define B_  16
#define N_  4096
#define M_  1024
#define K_  32

typedef __bf16 bf16x8 __attribute__((ext_vector_type(8)));
typedef __bf16 bf16x4 __attribute__((ext_vector_type(4)));
typedef float  f32x4  __attribute__((ext_vector_type(4)));
typedef float  f32x2  __attribute__((ext_vector_type(2)));

// ---------------------------------------------------------------------------
// Weight prep: transpose + cast to bf16, pad W1 K-dim 67->96 with zeros.
// ---------------------------------------------------------------------------
__global__ __launch_bounds__(256) void prep_weights(
    const float* __restrict__ W1, const float* __restrict__ W2,
    const float* __restrict__ W3,
    __bf16* __restrict__ w1t, __bf16* __restrict__ w2t, __bf16* __restrict__ w3t) {
  const int t = blockIdx.x * 256 + threadIdx.x;   // 0..32767
  if (t < 128 * 96) {
    const int n = t / 96, k = t % 96;
    w1t[t] = (k < 67) ? (__bf16)W1[k * 128 + n] : (__bf16)0.0f;
  }
  if (t < 128 * 128) {
    const int n = t >> 7, k = t & 127;
    w2t[t] = (__bf16)W2[k * 128 + n];
  }
  {
    const int n = t >> 7, k = t & 127;   // t < 256*128 always
    w3t[t] = (__bf16)W3[k * 256 + n];
  }
}

// ---------------------------------------------------------------------------
// FPS. One block per cloud, 256 threads, 16 points/thread in registers.
// - Distances via packed-f32 VOP3P (2 points/inst), per-component order
//   ((dx*dx + dy*dy) + dz*dz) with RN ops -> bit-exact vs numpy reference.
// - Argmax key u64 = (f32bits(D) << 32) | ~idx; max-key == (max D, tie->min idx).
// - Full-wave reduce entirely on the VALU pipe: DPP xor1/xor2/half_mirror/
//   mirror/row_bcast15/row_bcast31 (lane 63 holds wave max; bound_ctrl zero-fill
//   always loses since real keys have lo=~idx != 0).
// - Cross-wave: 4 partials in LDS; the 4 candidate positions are loaded in
//   parallel with the compare chain and selected by cndmask, so the next query
//   point never waits on a dependent LDS load.
// ---------------------------------------------------------------------------
__device__ __forceinline__ f32x2 pk_sub(f32x2 a, f32x2 b) {
  f32x2 d;
  asm("v_pk_add_f32 %0, %1, %2 neg_lo:[0,1] neg_hi:[0,1]" : "=v"(d) : "v"(a), "v"(b));
  return d;
}
__device__ __forceinline__ f32x2 pk_mul(f32x2 a, f32x2 b) {
  f32x2 d;
  asm("v_pk_mul_f32 %0, %1, %2" : "=v"(d) : "v"(a), "v"(b));
  return d;
}
__device__ __forceinline__ f32x2 pk_add(f32x2 a, f32x2 b) {
  f32x2 d;
  asm("v_pk_add_f32 %0, %1, %2" : "=v"(d) : "v"(a), "v"(b));
  return d;
}

template <int CTRL>
__device__ __forceinline__ unsigned long long dpp_max_u64(unsigned long long k) {
  unsigned lo = (unsigned)__builtin_amdgcn_update_dpp(0, (int)(unsigned)k,         CTRL, 0xF, 0xF, true);
  unsigned hi = (unsigned)__builtin_amdgcn_update_dpp(0, (int)(unsigned)(k >> 32), CTRL, 0xF, 0xF, true);
  unsigned long long p = ((unsigned long long)hi << 32) | lo;
  return p > k ? p : k;
}

__global__ __launch_bounds__(256) void fps_kernel(const float* __restrict__ pos,
                                                  int* __restrict__ fps_idx,
                                                  float* __restrict__ pos_s) {
  __shared__ alignas(16) float4 pp[N_];
  __shared__ alignas(32) unsigned long long sw[2][4];

  const int b   = blockIdx.x;
  const int tid = threadIdx.x;
  const float* pb = pos + (size_t)b * N_ * 3;
  for (int i = tid; i < N_; i += 256)
    pp[i] = make_float4(pb[3 * i], pb[3 * i + 1], pb[3 * i + 2], 0.0f);
  __syncthreads();

  f32x2 X2[8], Y2[8], Z2[8];
  float D[16];
  unsigned lo16[16];
  const unsigned ntid = ~(unsigned)tid;
#pragma unroll
  for (int j = 0; j < 8; j++) {
    float4 p0 = pp[tid + ((2 * j) << 8)];
    float4 p1 = pp[tid + ((2 * j + 1) << 8)];
    X2[j][0] = p0.x; X2[j][1] = p1.x;
    Y2[j][0] = p0.y; Y2[j][1] = p1.y;
    Z2[j][0] = p0.z; Z2[j][1] = p1.z;
    D[2 * j] = 1e30f; D[2 * j + 1] = 1e30f;
    lo16[2 * j]     = ntid - (unsigned)((2 * j) << 8);
    lo16[2 * j + 1] = ntid - (unsigned)((2 * j + 1) << 8);
  }

  float4 q = pp[0];
  if (tid == 0) {
    fps_idx[b * M_] = 0;
    float* o = pos_s + (size_t)b * M_ * 3;
    o[0] = q.x; o[1] = q.y; o[2] = q.z;
  }

  for (int i = 1; i < M_; i++) {
    f32x2 qx; qx[0] = q.x; qx[1] = q.x;
    f32x2 qy; qy[0] = q.y; qy[1] = q.y;
    f32x2 qz; qz[0] = q.z; qz[1] = q.z;
    unsigned long long key[16];
#pragma unroll
    for (int j = 0; j < 8; j++) {
      f32x2 dx = pk_sub(X2[j], qx);
      f32x2 dy = pk_sub(Y2[j], qy);
      f32x2 dz = pk_sub(Z2[j], qz);
      f32x2 t0 = pk_mul(dx, dx);
      f32x2 t1 = pk_mul(dy, dy);
      f32x2 s  = pk_add(t0, t1);
      f32x2 t2 = pk_mul(dz, dz);
      f32x2 d2 = pk_add(s, t2);
      D[2 * j]     = fminf(D[2 * j],     d2[0]);
      D[2 * j + 1] = fminf(D[2 * j + 1], d2[1]);
      key[2 * j]     = ((unsigned long long)__float_as_uint(D[2 * j])     << 32) | lo16[2 * j];
      key[2 * j + 1] = ((unsigned long long)__float_as_uint(D[2 * j + 1]) << 32) | lo16[2 * j + 1];
    }
    // per-thread tree reduce (depth 4; key ordering keeps first-occurrence ties)
#pragma unroll
    for (int s = 8; s > 0; s >>= 1)
#pragma unroll
      for (int k = 0; k < s; k++)
        if (key[k + s] > key[k]) key[k] = key[k + s];
    unsigned long long kk = key[0];

    // full-wave VALU-pipe butterfly/scan: lane 63 ends with the wave max
    kk = dpp_max_u64<0xB1>(kk);    // quad_perm [1,0,3,2]  (xor1)
    kk = dpp_max_u64<0x4E>(kk);    // quad_perm [2,3,0,1]  (xor2)
    kk = dpp_max_u64<0x141>(kk);   // row_half_mirror      (xor4)
    kk = dpp_max_u64<0x140>(kk);   // row_mirror           (xor8)
    kk = dpp_max_u64<0x142>(kk);   // row_bcast15  -> 32-group max at lanes 16-31/48-63
    kk = dpp_max_u64<0x143>(kk);   // row_bcast31  -> wave max at lanes 48-63

    const int par = i & 1;
    if ((tid & 63) == 63) sw[par][tid >> 6] = kk;
    __syncthreads();

    const ulonglong2 v01 = *(const ulonglong2*)&sw[par][0];
    const ulonglong2 v23 = *(const ulonglong2*)&sw[par][2];
    // load all 4 candidate positions in parallel with the compare chain
    const int c0 = (int)(~(unsigned)v01.x), c1 = (int)(~(unsigned)v01.y);
    const int c2 = (int)(~(unsigned)v23.x), c3 = (int)(~(unsigned)v23.y);
    float4 q0 = pp[c0], q1 = pp[c1], q2 = pp[c2], q3 = pp[c3];
    unsigned long long k01, k23; float4 q01, q23; int i01, i23;
    if (v01.y > v01.x) { k01 = v01.y; q01 = q1; i01 = c1; }
    else               { k01 = v01.x; q01 = q0; i01 = c0; }
    if (v23.y > v23.x) { k23 = v23.y; q23 = q3; i23 = c3; }
    else               { k23 = v23.x; q23 = q2; i23 = c2; }
    int cur;
    if (k23 > k01) { q = q23; cur = i23; }
    else           { q = q01; cur = i01; }

    if (tid == 0) {
      fps_idx[b * M_ + i] = cur;
      float* o = pos_s + ((size_t)b * M_ + i) * 3;
      o[0] = q.x; o[1] = q.y; o[2] = q.z;
    }
  }
}

// ---------------------------------------------------------------------------
// kNN: one wave per centroid (4 waves/block share staged cloud in LDS).
// Lanes 0..31 hold the current 32 best keys, sorted ascending.
// key = (f32bits(d2) << 32) | idx  -> lexicographic (d2, idx) == top_k order.
// Insertion of a non-qualifying candidate is a provable no-op (pos_i >= 32),
// so the tile-start threshold needs no per-candidate refresh.
// ---------------------------------------------------------------------------
__global__ __launch_bounds__(256) void knn_kernel(const float* __restrict__ pos,
                                                  const int* __restrict__ fps_idx,
                                                  unsigned short* __restrict__ nbr) {
  __shared__ alignas(16) float4 pp[N_];
  const int b    = blockIdx.x >> 8;
  const int mset = blockIdx.x & 255;
  const int tid  = threadIdx.x;
  const int w    = tid >> 6;
  const int lane = tid & 63;

  const float* pb = pos + (size_t)b * N_ * 3;
  for (int i = tid; i < N_; i += 256)
    pp[i] = make_float4(pb[3 * i], pb[3 * i + 1], pb[3 * i + 2], 0.0f);
  __syncthreads();

  const int m  = mset * 4 + w;
  const int ci = fps_idx[b * M_ + m];
  const float4 c = pp[ci];

  unsigned long long rkey = ~0ull;   // lanes >=32 stay at MAX forever

  for (int t = 0; t < N_ / 64; t++) {
    const int j = t * 64 + lane;
    const float4 p = pp[j];
    float dx = __fsub_rn(p.x, c.x);
    float dy = __fsub_rn(p.y, c.y);
    float dz = __fsub_rn(p.z, c.z);
    float d  = __fadd_rn(__fadd_rn(__fmul_rn(dx, dx), __fmul_rn(dy, dy)),
                         __fmul_rn(dz, dz));
    const unsigned long long k64 =
        ((unsigned long long)__float_as_uint(d) << 32) | (unsigned int)j;

    const unsigned long long wk = __shfl(rkey, 31);   // tile-start threshold
    unsigned long long mask = __ballot(k64 < wk);
    while (mask) {
      const int src = __ffsll((unsigned long long)mask) - 1;
      mask &= mask - 1;
      const unsigned long long cand = __shfl(k64, src);
      const int pos_i = (int)__popcll(__ballot(rkey < cand));  // >=32 -> no-op
      const unsigned long long sh = __shfl_up(rkey, 1);
      if (lane < 32) {
        if (lane == pos_i)      rkey = cand;
        else if (lane > pos_i)  rkey = sh;
      }
    }
  }
  if (lane < 32)
    nbr[(size_t)(b * M_ + m) * K_ + lane] = (unsigned short)(rkey & 0xFFFFull);
}

// ---------------------------------------------------------------------------
// Fused gather + MLP + maxpool. Block = 4 waves = 4 centroids (128 rows).
// ---------------------------------------------------------------------------
#define AST 136

__global__ __launch_bounds__(256) void mlp_kernel(
    const float* __restrict__ x, const float* __restrict__ pos,
    const float* __restrict__ b1, const float* __restrict__ b2,
    const float* __restrict__ b3,
    const unsigned short* __restrict__ nbr,
    const __bf16* __restrict__ w1t, const __bf16* __restrict__ w2t,
    const __bf16* __restrict__ w3t,
    float* __restrict__ out, const float* __restrict__ pos_s) {
  __shared__ alignas(16) __bf16 bufA[128 * AST];   // msg (k=0..95), later act2 (k=0..127)
  __shared__ alignas(16) __bf16 bufB[128 * AST];   // act1

  const int b    = blockIdx.x >> 8;
  const int mset = blockIdx.x & 255;
  const int w    = threadIdx.x >> 6;
  const int lane = threadIdx.x & 63;
  const int m    = mset * 4 + w;

  // ---- gather: 2 lanes per row ----
  {
    const int rl   = lane >> 1;      // neighbor slot 0..31
    const int half = lane & 1;
    const int r    = w * 32 + rl;
    const int nj   = (int)nbr[(size_t)(b * M_ + m) * K_ + rl];
    const float4* xr = (const float4*)(x + ((size_t)(b * N_ + nj)) * 64 + half * 32);
    __bf16* dst = &bufA[r * AST + half * 32];
#pragma unroll
    for (int t = 0; t < 8; t++) {
      float4 v = xr[t];
      bf16x4 u;
      u[0] = (__bf16)v.x; u[1] = (__bf16)v.y; u[2] = (__bf16)v.z; u[3] = (__bf16)v.w;
      *(bf16x4*)(dst + t * 4) = u;
    }
    bf16x8 z;
#pragma unroll
    for (int q2 = 0; q2 < 8; q2++) z[q2] = (__bf16)0.0f;
    if (half == 0) {
      const float* pj = pos + ((size_t)(b * N_ + nj)) * 3;
      const float* ps = pos_s + ((size_t)(b * M_ + m)) * 3;
      bf16x8 u = z;
      u[0] = (__bf16)(pj[0] - ps[0]);
      u[1] = (__bf16)(pj[1] - ps[1]);
      u[2] = (__bf16)(pj[2] - ps[2]);
      *(bf16x8*)&bufA[r * AST + 64] = u;
      *(bf16x8*)&bufA[r * AST + 72] = z;
    } else {
      *(bf16x8*)&bufA[r * AST + 80] = z;
      *(bf16x8*)&bufA[r * AST + 88] = z;
    }
  }
  __syncthreads();

  const int lrow  = lane & 15;
  const int lk8   = (lane >> 4) << 3;   // k offset within 32-step
  const int orow  = (lane >> 4) << 2;   // D row base within tile
  const int rbase = w * 32;

  // ---- layer 1: msg(96) @ W1 -> relu -> bufB(128) ----
  {
    f32x4 acc0[8], acc1[8];
#pragma unroll
    for (int n = 0; n < 8; n++) {
      const float bv = b1[n * 16 + lrow];
      f32x4 a = {bv, bv, bv, bv};
      acc0[n] = a; acc1[n] = a;
    }
#pragma unroll
    for (int s = 0; s < 3; s++) {
      bf16x8 a0 = *(const bf16x8*)&bufA[(rbase + lrow) * AST + s * 32 + lk8];
      bf16x8 a1 = *(const bf16x8*)&bufA[(rbase + 16 + lrow) * AST + s * 32 + lk8];
#pragma unroll
      for (int n = 0; n < 8; n++) {
        bf16x8 bb = *(const bf16x8*)&w1t[(n * 16 + lrow) * 96 + s * 32 + lk8];
        acc0[n] = __builtin_amdgcn_mfma_f32_16x16x32_bf16(a0, bb, acc0[n], 0, 0, 0);
        acc1[n] = __builtin_amdgcn_mfma_f32_16x16x32_bf16(a1, bb, acc1[n], 0, 0, 0);
      }
    }
#pragma unroll
    for (int n = 0; n < 8; n++)
#pragma unroll
      for (int j = 0; j < 4; j++) {
        bufB[(rbase + orow + j) * AST + n * 16 + lrow]      = (__bf16)fmaxf(acc0[n][j], 0.0f);
        bufB[(rbase + 16 + orow + j) * AST + n * 16 + lrow] = (__bf16)fmaxf(acc1[n][j], 0.0f);
      }
  }
  __syncthreads();

  // ---- layer 2: bufB(128) @ W2 -> relu -> bufA(128) ----
  {
    f32x4 acc0[8], acc1[8];
#pragma unroll
    for (int n = 0; n < 8; n++) {
      const float bv = b2[n * 16 + lrow];
      f32x4 a = {bv, bv, bv, bv};
      acc0[n] = a; acc1[n] = a;
    }
#pragma unroll
    for (int s = 0; s < 4; s++) {
      bf16x8 a0 = *(const bf16x8*)&bufB[(rbase + lrow) * AST + s * 32 + lk8];
      bf16x8 a1 = *(const bf16x8*)&bufB[(rbase + 16 + lrow) * AST + s * 32 + lk8];
#pragma unroll
      for (int n = 0; n < 8; n++) {
        bf16x8 bb = *(const bf16x8*)&w2t[(n * 16 + lrow) * 128 + s * 32 + lk8];
        acc0[n] = __builtin_amdgcn_mfma_f32_16x16x32_bf16(a0, bb, acc0[n], 0, 0, 0);
        acc1[n] = __builtin_amdgcn_mfma_f32_16x16x32_bf16(a1, bb, acc1[n], 0, 0, 0);
      }
    }
#pragma unroll
    for (int n = 0; n < 8; n++)
#pragma unroll
      for (int j = 0; j < 4; j++) {
        bufA[(rbase + orow + j) * AST + n * 16 + lrow]      = (__bf16)fmaxf(acc0[n][j], 0.0f);
        bufA[(rbase + 16 + orow + j) * AST + n * 16 + lrow] = (__bf16)fmaxf(acc1[n][j], 0.0f);
      }
  }
  __syncthreads();

  // ---- layer 3 (two 128-col halves) + maxpool over the wave's 32 rows ----
  for (int nh = 0; nh < 2; nh++) {
    f32x4 acc0[8], acc1[8];
#pragma unroll
    for (int n = 0; n < 8; n++) {
      const float bv = b3[nh * 128 + n * 16 + lrow];
      f32x4 a = {bv, bv, bv, bv};
      acc0[n] = a; acc1[n] = a;
    }
#pragma unroll
    for (int s = 0; s < 4; s++) {
      bf16x8 a0 = *(const bf16x8*)&bufA[(rbase + lrow) * AST + s * 32 + lk8];
      bf16x8 a1 = *(const bf16x8*)&bufA[(rbase + 16 + lrow) * AST + s * 32 + lk8];
#pragma unroll
      for (int n = 0; n < 8; n++) {
        bf16x8 bb = *(const bf16x8*)&w3t[(nh * 128 + n * 16 + lrow) * 128 + s * 32 + lk8];
        acc0[n] = __builtin_amdgcn_mfma_f32_16x16x32_bf16(a0, bb, acc0[n], 0, 0, 0);
        acc1[n] = __builtin_amdgcn_mfma_f32_16x16x32_bf16(a1, bb, acc1[n], 0, 0, 0);
      }
    }
#pragma unroll
    for (int n = 0; n < 8; n++) {
      float v = fmaxf(fmaxf(fmaxf(acc0[n][0], acc0[n][1]), fmaxf(acc0[n][2], acc0[n][3])),
                      fmaxf(fmaxf(acc1[n][0], acc1[n][1]), fmaxf(acc1[n][2], acc1[n][3])));
      v = fmaxf(v, __shfl_xor(v, 16));
      v = fmaxf(v, __shfl_xor(v, 32));
      v = fmaxf(v, 0.0f);   // relu commutes with max
      if (lane < 16)
        out[((size_t)(b * M_ + m)) * 256 + nh * 128 + n * 16 + lane] = v;
    }
  }
}

// ---------------------------------------------------------------------------
extern "C" void kernel_launch(void* const* d_in, const int* in_sizes, int n_in,
                              void* d_out, int out_size, void* d_ws, size_t ws_size,
                              hipStream_t stream) {
  const float* x   = (const float*)d_in[0];
  const float* pos = (const float*)d_in[1];
  const float* W1  = (const float*)d_in[2];
  const float* b1  = (const float*)d_in[3];
  const float* W2  = (const float*)d_in[4];
  const float* b2  = (const float*)d_in[5];
  const float* W3  = (const float*)d_in[6];
  const float* b3  = (const float*)d_in[7];

  float* out   = (float*)d_out;
  float* pos_s = out + (size_t)B_ * M_ * 256;

  char* ws = (char*)d_ws;
  int*            fps_idx = (int*)ws;                              // 65536 B
  unsigned short* nbr     = (unsigned short*)(ws + 65536);         // 1048576 B
  __bf16*         w1t     = (__bf16*)(ws + 1114112);               // 24576 B
  __bf16*         w2t     = (__bf16*)(ws + 1138688);               // 32768 B
  __bf16*         w3t     = (__bf16*)(ws + 1171456);               // 65536 B

  prep_weights<<<dim3(128), dim3(256), 0, stream>>>(W1, W2, W3, w1t, w2t, w3t);
  fps_kernel<<<dim3(B_), dim3(256), 0, stream>>>(pos, fps_idx, pos_s);
  knn_kernel<<<dim3(B_ * (M_ / 4)), dim3(256), 0, stream>>>(pos, fps_idx, nbr);
  mlp_kernel<<<dim3(B_ * (M_ / 4)), dim3(256), 0, stream>>>(
      x, pos, b1, b2, b3, nbr, w1t, w2t, w3t, out, pos_s);
}

// Round 4
// 1059.694 us; speedup vs baseline: 1.5788x; 1.0322x over previous
//
#include <hip/hip_runtime.h>

// SAModule (PointNet++ set-abstraction): FPS -> kNN(32) -> [x||rel] MLP(67->128->128->256) -> max over K.
// B=16, N=4096, C=64, M=1024, K=32.
// d_in: x, pos, W1, b1, W2, b2, W3, b3 (all f32)
// d_out: out[16*1024*256] f32 then pos_s[16*1024*3] f32.

#define B_  16
#define N_  4096
#define M_  1024
#define K_  32

typedef __bf16 bf16x8 __attribute__((ext_vector_type(8)));
typedef __bf16 bf16x4 __attribute__((ext_vector_type(4)));
typedef float  f32x4  __attribute__((ext_vector_type(4)));
typedef float  f32x2  __attribute__((ext_vector_type(2)));

// ---------------------------------------------------------------------------
// Weight prep: transpose + cast to bf16, pad W1 K-dim 67->96 with zeros.
// ---------------------------------------------------------------------------
__global__ __launch_bounds__(256) void prep_weights(
    const float* __restrict__ W1, const float* __restrict__ W2,
    const float* __restrict__ W3,
    __bf16* __restrict__ w1t, __bf16* __restrict__ w2t, __bf16* __restrict__ w3t) {
  const int t = blockIdx.x * 256 + threadIdx.x;   // 0..32767
  if (t < 128 * 96) {
    const int n = t / 96, k = t % 96;
    w1t[t] = (k < 67) ? (__bf16)W1[k * 128 + n] : (__bf16)0.0f;
  }
  if (t < 128 * 128) {
    const int n = t >> 7, k = t & 127;
    w2t[t] = (__bf16)W2[k * 128 + n];
  }
  {
    const int n = t >> 7, k = t & 127;   // t < 256*128 always
    w3t[t] = (__bf16)W3[k * 256 + n];
  }
}

// ---------------------------------------------------------------------------
// FPS. One block per cloud, 512 threads (8 waves -> 2 waves/SIMD for latency
// overlap), 8 points/thread in registers.
// - Distances via packed-f32 VOP3P, component order ((dx*dx+dy*dy)+dz*dz)
//   with RN ops -> bit-exact vs numpy reference.
// - Argmax key u64 = (f32bits(D)<<32) | ~idx; max-key == (max D, tie->min idx).
// - Wave reduce on VALU pipe via DPP; cross-wave via 8 LDS partials with
//   parallel candidate-position prefetch (no dependent second LDS load).
// ---------------------------------------------------------------------------
__device__ __forceinline__ f32x2 pk_sub(f32x2 a, f32x2 b) {
  f32x2 d;
  asm("v_pk_add_f32 %0, %1, %2 neg_lo:[0,1] neg_hi:[0,1]" : "=v"(d) : "v"(a), "v"(b));
  return d;
}
__device__ __forceinline__ f32x2 pk_mul(f32x2 a, f32x2 b) {
  f32x2 d;
  asm("v_pk_mul_f32 %0, %1, %2" : "=v"(d) : "v"(a), "v"(b));
  return d;
}
__device__ __forceinline__ f32x2 pk_add(f32x2 a, f32x2 b) {
  f32x2 d;
  asm("v_pk_add_f32 %0, %1, %2" : "=v"(d) : "v"(a), "v"(b));
  return d;
}

template <int CTRL>
__device__ __forceinline__ unsigned long long dpp_max_u64(unsigned long long k) {
  unsigned lo = (unsigned)__builtin_amdgcn_update_dpp(0, (int)(unsigned)k,         CTRL, 0xF, 0xF, true);
  unsigned hi = (unsigned)__builtin_amdgcn_update_dpp(0, (int)(unsigned)(k >> 32), CTRL, 0xF, 0xF, true);
  unsigned long long p = ((unsigned long long)hi << 32) | lo;
  return p > k ? p : k;
}

__global__ __launch_bounds__(512) void fps_kernel(const float* __restrict__ pos,
                                                  int* __restrict__ fps_idx,
                                                  float* __restrict__ pos_s) {
  __shared__ alignas(16) float4 pp[N_];
  __shared__ alignas(32) unsigned long long sw[2][8];

  const int b   = blockIdx.x;
  const int tid = threadIdx.x;
  const float* pb = pos + (size_t)b * N_ * 3;
  for (int i = tid; i < N_; i += 512)
    pp[i] = make_float4(pb[3 * i], pb[3 * i + 1], pb[3 * i + 2], 0.0f);
  __syncthreads();

  f32x2 X2[4], Y2[4], Z2[4];
  float D[8];
  unsigned lo16[8];
  const unsigned ntid = ~(unsigned)tid;
#pragma unroll
  for (int j = 0; j < 4; j++) {
    float4 p0 = pp[tid + ((2 * j) << 9)];
    float4 p1 = pp[tid + ((2 * j + 1) << 9)];
    X2[j][0] = p0.x; X2[j][1] = p1.x;
    Y2[j][0] = p0.y; Y2[j][1] = p1.y;
    Z2[j][0] = p0.z; Z2[j][1] = p1.z;
    D[2 * j] = 1e30f; D[2 * j + 1] = 1e30f;
    lo16[2 * j]     = ntid - (unsigned)((2 * j) << 9);
    lo16[2 * j + 1] = ntid - (unsigned)((2 * j + 1) << 9);
  }

  float4 q = pp[0];
  if (tid == 0) {
    fps_idx[b * M_] = 0;
    float* o = pos_s + (size_t)b * M_ * 3;
    o[0] = q.x; o[1] = q.y; o[2] = q.z;
  }

  for (int i = 1; i < M_; i++) {
    f32x2 qx; qx[0] = q.x; qx[1] = q.x;
    f32x2 qy; qy[0] = q.y; qy[1] = q.y;
    f32x2 qz; qz[0] = q.z; qz[1] = q.z;
    unsigned long long key[8];
#pragma unroll
    for (int j = 0; j < 4; j++) {
      f32x2 dx = pk_sub(X2[j], qx);
      f32x2 dy = pk_sub(Y2[j], qy);
      f32x2 dz = pk_sub(Z2[j], qz);
      f32x2 t0 = pk_mul(dx, dx);
      f32x2 t1 = pk_mul(dy, dy);
      f32x2 s  = pk_add(t0, t1);
      f32x2 t2 = pk_mul(dz, dz);
      f32x2 d2 = pk_add(s, t2);
      D[2 * j]     = fminf(D[2 * j],     d2[0]);
      D[2 * j + 1] = fminf(D[2 * j + 1], d2[1]);
      key[2 * j]     = ((unsigned long long)__float_as_uint(D[2 * j])     << 32) | lo16[2 * j];
      key[2 * j + 1] = ((unsigned long long)__float_as_uint(D[2 * j + 1]) << 32) | lo16[2 * j + 1];
    }
#pragma unroll
    for (int s = 4; s > 0; s >>= 1)
#pragma unroll
      for (int k = 0; k < s; k++)
        if (key[k + s] > key[k]) key[k] = key[k + s];
    unsigned long long kk = key[0];

    // full-wave VALU-pipe reduce: lane 63 ends with the wave max
    kk = dpp_max_u64<0xB1>(kk);    // quad_perm xor1
    kk = dpp_max_u64<0x4E>(kk);    // quad_perm xor2
    kk = dpp_max_u64<0x141>(kk);   // row_half_mirror (xor4)
    kk = dpp_max_u64<0x140>(kk);   // row_mirror (xor8)
    kk = dpp_max_u64<0x142>(kk);   // row_bcast15
    kk = dpp_max_u64<0x143>(kk);   // row_bcast31

    const int par = i & 1;
    if ((tid & 63) == 63) sw[par][tid >> 6] = kk;
    __syncthreads();

    const unsigned long long* s8 = sw[par];
    unsigned long long k8[8]; int c8[8]; float4 q8[8];
#pragma unroll
    for (int j = 0; j < 8; j++) k8[j] = s8[j];
#pragma unroll
    for (int j = 0; j < 8; j++) { c8[j] = (int)(~(unsigned)k8[j]); q8[j] = pp[c8[j]]; }
#pragma unroll
    for (int s = 4; s > 0; s >>= 1)
#pragma unroll
      for (int j = 0; j < s; j++)
        if (k8[j + s] > k8[j]) { k8[j] = k8[j + s]; c8[j] = c8[j + s]; q8[j] = q8[j + s]; }
    q = q8[0];
    const int cur = c8[0];

    if (tid == 0) {
      fps_idx[b * M_ + i] = cur;
      float* o = pos_s + ((size_t)b * M_ + i) * 3;
      o[0] = q.x; o[1] = q.y; o[2] = q.z;
    }
  }
}

// ---------------------------------------------------------------------------
// kNN: one wave per centroid (4 waves/block share staged cloud in LDS).
// key = (f32bits(d2)<<32) | idx -> lexicographic (d2, idx) == top_k order.
// Pass A: all 64 per-lane distances (kept in regs) + per-lane min key.
// Bitonic-sort the 64 lane-min keys across lanes; T0 = lane-31 key is the
// 32nd-smallest lane-min >= true 32nd key (32 lanes each contribute >=1
// candidate <= T0). Seed the sorted list with those 32 keys (genuine
// candidates, list max == T0). Pass B scans all candidates, skipping each
// lane's seeded key (if it was evicted it is provably not top-32, so the
// skip stays exact); expected non-seed insertions ~13.
// ---------------------------------------------------------------------------
__global__ __launch_bounds__(256) void knn_kernel(const float* __restrict__ pos,
                                                  const int* __restrict__ fps_idx,
                                                  unsigned short* __restrict__ nbr) {
  __shared__ alignas(16) float4 pp[N_];
  const int b    = blockIdx.x >> 8;
  const int mset = blockIdx.x & 255;
  const int tid  = threadIdx.x;
  const int w    = tid >> 6;
  const int lane = tid & 63;

  const float* pb = pos + (size_t)b * N_ * 3;
  for (int i = tid; i < N_; i += 256)
    pp[i] = make_float4(pb[3 * i], pb[3 * i + 1], pb[3 * i + 2], 0.0f);
  __syncthreads();

  const int m  = mset * 4 + w;
  const int ci = fps_idx[b * M_ + m];
  const float4 c = pp[ci];

  // ---- Pass A: distances + lane-min key ----
  float d2v[64];
  unsigned long long kmin = ~0ull;
#pragma unroll
  for (int t = 0; t < 64; t++) {
    const int j = t * 64 + lane;
    const float4 p = pp[j];
    float dx = __fsub_rn(p.x, c.x);
    float dy = __fsub_rn(p.y, c.y);
    float dz = __fsub_rn(p.z, c.z);
    float d  = __fadd_rn(__fadd_rn(__fmul_rn(dx, dx), __fmul_rn(dy, dy)),
                         __fmul_rn(dz, dz));
    d2v[t] = d;
    const unsigned long long k64 =
        ((unsigned long long)__float_as_uint(d) << 32) | (unsigned int)j;
    if (k64 < kmin) kmin = k64;
  }

  // ---- bitonic sort of the 64 lane-min keys (ascending across lanes) ----
  unsigned long long sk = kmin;
#pragma unroll
  for (int size = 2; size <= 64; size <<= 1) {
#pragma unroll
    for (int stride = size >> 1; stride > 0; stride >>= 1) {
      const unsigned long long other = __shfl_xor(sk, stride);
      const bool up      = ((lane & size) == 0);
      const bool lowhalf = ((lane & stride) == 0);
      const bool takeMin = (up == lowhalf);
      const bool sw      = takeMin ? (other < sk) : (other > sk);
      if (sw) sk = other;
    }
  }
  const unsigned long long T0 = __shfl(sk, 31);
  const bool seeded = (kmin <= T0);

  // seed list: lanes 0..31 hold the 32 smallest lane-min keys, sorted
  unsigned long long rkey = (lane < 32) ? sk : ~0ull;
  unsigned long long wk   = T0;   // == current list max

  // ---- Pass B: scan, skipping seeded keys ----
#pragma unroll
  for (int t = 0; t < 64; t++) {
    const int j = t * 64 + lane;
    const unsigned long long k64 =
        ((unsigned long long)__float_as_uint(d2v[t]) << 32) | (unsigned int)j;
    const bool skip = seeded && (k64 == kmin);
    unsigned long long mask = __ballot((k64 < wk) && !skip);
    if (mask) {
      while (mask) {
        const int src = __ffsll((unsigned long long)mask) - 1;
        mask &= mask - 1;
        const unsigned long long cand = __shfl(k64, src);
        const int pos_i = (int)__popcll(__ballot(rkey < cand));  // >=32 -> no-op
        const unsigned long long sh = __shfl_up(rkey, 1);
        if (lane < 32) {
          if (lane == pos_i)      rkey = cand;
          else if (lane > pos_i)  rkey = sh;
        }
      }
      wk = __shfl(rkey, 31);
    }
  }
  if (lane < 32)
    nbr[(size_t)(b * M_ + m) * K_ + lane] = (unsigned short)(rkey & 0xFFFFull);
}

// ---------------------------------------------------------------------------
// Fused gather + MLP + maxpool. Block = 4 waves = 4 centroids (128 rows).
// ---------------------------------------------------------------------------
#define AST 136

__global__ __launch_bounds__(256) void mlp_kernel(
    const float* __restrict__ x, const float* __restrict__ pos,
    const float* __restrict__ b1, const float* __restrict__ b2,
    const float* __restrict__ b3,
    const unsigned short* __restrict__ nbr,
    const __bf16* __restrict__ w1t, const __bf16* __restrict__ w2t,
    const __bf16* __restrict__ w3t,
    float* __restrict__ out, const float* __restrict__ pos_s) {
  __shared__ alignas(16) __bf16 bufA[128 * AST];   // msg (k=0..95), later act2 (k=0..127)
  __shared__ alignas(16) __bf16 bufB[128 * AST];   // act1

  const int b    = blockIdx.x >> 8;
  const int mset = blockIdx.x & 255;
  const int w    = threadIdx.x >> 6;
  const int lane = threadIdx.x & 63;
  const int m    = mset * 4 + w;

  // ---- gather: 2 lanes per row ----
  {
    const int rl   = lane >> 1;      // neighbor slot 0..31
    const int half = lane & 1;
    const int r    = w * 32 + rl;
    const int nj   = (int)nbr[(size_t)(b * M_ + m) * K_ + rl];
    const float4* xr = (const float4*)(x + ((size_t)(b * N_ + nj)) * 64 + half * 32);
    __bf16* dst = &bufA[r * AST + half * 32];
#pragma unroll
    for (int t = 0; t < 8; t++) {
      float4 v = xr[t];
      bf16x4 u;
      u[0] = (__bf16)v.x; u[1] = (__bf16)v.y; u[2] = (__bf16)v.z; u[3] = (__bf16)v.w;
      *(bf16x4*)(dst + t * 4) = u;
    }
    bf16x8 z;
#pragma unroll
    for (int q2 = 0; q2 < 8; q2++) z[q2] = (__bf16)0.0f;
    if (half == 0) {
      const float* pj = pos + ((size_t)(b * N_ + nj)) * 3;
      const float* ps = pos_s + ((size_t)(b * M_ + m)) * 3;
      bf16x8 u = z;
      u[0] = (__bf16)(pj[0] - ps[0]);
      u[1] = (__bf16)(pj[1] - ps[1]);
      u[2] = (__bf16)(pj[2] - ps[2]);
      *(bf16x8*)&bufA[r * AST + 64] = u;
      *(bf16x8*)&bufA[r * AST + 72] = z;
    } else {
      *(bf16x8*)&bufA[r * AST + 80] = z;
      *(bf16x8*)&bufA[r * AST + 88] = z;
    }
  }
  __syncthreads();

  const int lrow  = lane & 15;
  const int lk8   = (lane >> 4) << 3;   // k offset within 32-step
  const int orow  = (lane >> 4) << 2;   // D row base within tile
  const int rbase = w * 32;

  // ---- layer 1: msg(96) @ W1 -> relu -> bufB(128) ----
  {
    f32x4 acc0[8], acc1[8];
#pragma unroll
    for (int n = 0; n < 8; n++) {
      const float bv = b1[n * 16 + lrow];
      f32x4 a = {bv, bv, bv, bv};
      acc0[n] = a; acc1[n] = a;
    }
#pragma unroll
    for (int s = 0; s < 3; s++) {
      bf16x8 a0 = *(const bf16x8*)&bufA[(rbase + lrow) * AST + s * 32 + lk8];
      bf16x8 a1 = *(const bf16x8*)&bufA[(rbase + 16 + lrow) * AST + s * 32 + lk8];
#pragma unroll
      for (int n = 0; n < 8; n++) {
        bf16x8 bb = *(const bf16x8*)&w1t[(n * 16 + lrow) * 96 + s * 32 + lk8];
        acc0[n] = __builtin_amdgcn_mfma_f32_16x16x32_bf16(a0, bb, acc0[n], 0, 0, 0);
        acc1[n] = __builtin_amdgcn_mfma_f32_16x16x32_bf16(a1, bb, acc1[n], 0, 0, 0);
      }
    }
#pragma unroll
    for (int n = 0; n < 8; n++)
#pragma unroll
      for (int j = 0; j < 4; j++) {
        bufB[(rbase + orow + j) * AST + n * 16 + lrow]      = (__bf16)fmaxf(acc0[n][j], 0.0f);
        bufB[(rbase + 16 + orow + j) * AST + n * 16 + lrow] = (__bf16)fmaxf(acc1[n][j], 0.0f);
      }
  }
  __syncthreads();

  // ---- layer 2: bufB(128) @ W2 -> relu -> bufA(128) ----
  {
    f32x4 acc0[8], acc1[8];
#pragma unroll
    for (int n = 0; n < 8; n++) {
      const float bv = b2[n * 16 + lrow];
      f32x4 a = {bv, bv, bv, bv};
      acc0[n] = a; acc1[n] = a;
    }
#pragma unroll
    for (int s = 0; s < 4; s++) {
      bf16x8 a0 = *(const bf16x8*)&bufB[(rbase + lrow) * AST + s * 32 + lk8];
      bf16x8 a1 = *(const bf16x8*)&bufB[(rbase + 16 + lrow) * AST + s * 32 + lk8];
#pragma unroll
      for (int n = 0; n < 8; n++) {
        bf16x8 bb = *(const bf16x8*)&w2t[(n * 16 + lrow) * 128 + s * 32 + lk8];
        acc0[n] = __builtin_amdgcn_mfma_f32_16x16x32_bf16(a0, bb, acc0[n], 0, 0, 0);
        acc1[n] = __builtin_amdgcn_mfma_f32_16x16x32_bf16(a1, bb, acc1[n], 0, 0, 0);
      }
    }
#pragma unroll
    for (int n = 0; n < 8; n++)
#pragma unroll
      for (int j = 0; j < 4; j++) {
        bufA[(rbase + orow + j) * AST + n * 16 + lrow]      = (__bf16)fmaxf(acc0[n][j], 0.0f);
        bufA[(rbase + 16 + orow + j) * AST + n * 16 + lrow] = (__bf16)fmaxf(acc1[n][j], 0.0f);
      }
  }
  __syncthreads();

  // ---- layer 3 (two 128-col halves) + maxpool over the wave's 32 rows ----
  for (int nh = 0; nh < 2; nh++) {
    f32x4 acc0[8], acc1[8];
#pragma unroll
    for (int n = 0; n < 8; n++) {
      const float bv = b3[nh * 128 + n * 16 + lrow];
      f32x4 a = {bv, bv, bv, bv};
      acc0[n] = a; acc1[n] = a;
    }
#pragma unroll
    for (int s = 0; s < 4; s++) {
      bf16x8 a0 = *(const bf16x8*)&bufA[(rbase + lrow) * AST + s * 32 + lk8];
      bf16x8 a1 = *(const bf16x8*)&bufA[(rbase + 16 + lrow) * AST + s * 32 + lk8];
#pragma unroll
      for (int n = 0; n < 8; n++) {
        bf16x8 bb = *(const bf16x8*)&w3t[(nh * 128 + n * 16 + lrow) * 128 + s * 32 + lk8];
        acc0[n] = __builtin_amdgcn_mfma_f32_16x16x32_bf16(a0, bb, acc0[n], 0, 0, 0);
        acc1[n] = __builtin_amdgcn_mfma_f32_16x16x32_bf16(a1, bb, acc1[n], 0, 0, 0);
      }
    }
#pragma unroll
    for (int n = 0; n < 8; n++) {
      float v = fmaxf(fmaxf(fmaxf(acc0[n][0], acc0[n][1]), fmaxf(acc0[n][2], acc0[n][3])),
                      fmaxf(fmaxf(acc1[n][0], acc1[n][1]), fmaxf(acc1[n][2], acc1[n][3])));
      v = fmaxf(v, __shfl_xor(v, 16));
      v = fmaxf(v, __shfl_xor(v, 32));
      v = fmaxf(v, 0.0f);   // relu commutes with max
      if (lane < 16)
        out[((size_t)(b * M_ + m)) * 256 + nh * 128 + n * 16 + lane] = v;
    }
  }
}

// ---------------------------------------------------------------------------
extern "C" void kernel_launch(void* const* d_in, const int* in_sizes, int n_in,
                              void* d_out, int out_size, void* d_ws, size_t ws_size,
                              hipStream_t stream) {
  const float* x   = (const float*)d_in[0];
  const float* pos = (const float*)d_in[1];
  const float* W1  = (const float*)d_in[2];
  const float* b1  = (const float*)d_in[3];
  const float* W2  = (const float*)d_in[4];
  const float* b2  = (const float*)d_in[5];
  const float* W3  = (const float*)d_in[6];
  const float* b3  = (const float*)d_in[7];

  float* out   = (float*)d_out;
  float* pos_s = out + (size_t)B_ * M_ * 256;

  char* ws = (char*)d_ws;
  int*            fps_idx = (int*)ws;                              // 65536 B
  unsigned short* nbr     = (unsigned short*)(ws + 65536);         // 1048576 B
  __bf16*         w1t     = (__bf16*)(ws + 1114112);               // 24576 B
  __bf16*         w2t     = (__bf16*)(ws + 1138688);               // 32768 B
  __bf16*         w3t     = (__bf16*)(ws + 1171456);               // 65536 B

  prep_weights<<<dim3(128), dim3(256), 0, stream>>>(W1, W2, W3, w1t, w2t, w3t);
  fps_kernel<<<dim3(B_), dim3(512), 0, stream>>>(pos, fps_idx, pos_s);
  knn_kernel<<<dim3(B_ * (M_ / 4)), dim3(256), 0, stream>>>(pos, fps_idx, nbr);
  mlp_kernel<<<dim3(B_ * (M_ / 4)), dim3(256), 0, stream>>>(
      x, pos, b1, b2, b3, nbr, w1t, w2t, w3t, out, pos_s);
}

// Round 5
// 812.612 us; speedup vs baseline: 2.0589x; 1.3041x over previous
//
#include <hip/hip_runtime.h>

// SAModule (PointNet++ set-abstraction): FPS -> kNN(32) -> [x||rel] MLP(67->128->128->256) -> max over K.
// B=16, N=4096, C=64, M=1024, K=32.
// d_in: x, pos, W1, b1, W2, b2, W3, b3 (all f32)
// d_out: out[16*1024*256] f32 then pos_s[16*1024*3] f32.

#define B_  16
#define N_  4096
#define M_  1024
#define K_  32

typedef __bf16 bf16x8 __attribute__((ext_vector_type(8)));
typedef __bf16 bf16x4 __attribute__((ext_vector_type(4)));
typedef float  f32x4  __attribute__((ext_vector_type(4)));
typedef float  f32x2  __attribute__((ext_vector_type(2)));

// ---------------------------------------------------------------------------
// Weight prep: transpose + cast to bf16, pad W1 K-dim 67->96 with zeros.
// ---------------------------------------------------------------------------
__global__ __launch_bounds__(256) void prep_weights(
    const float* __restrict__ W1, const float* __restrict__ W2,
    const float* __restrict__ W3,
    __bf16* __restrict__ w1t, __bf16* __restrict__ w2t, __bf16* __restrict__ w3t) {
  const int t = blockIdx.x * 256 + threadIdx.x;   // 0..32767
  if (t < 128 * 96) {
    const int n = t / 96, k = t % 96;
    w1t[t] = (k < 67) ? (__bf16)W1[k * 128 + n] : (__bf16)0.0f;
  }
  if (t < 128 * 128) {
    const int n = t >> 7, k = t & 127;
    w2t[t] = (__bf16)W2[k * 128 + n];
  }
  {
    const int n = t >> 7, k = t & 127;   // t < 256*128 always
    w3t[t] = (__bf16)W3[k * 256 + n];
  }
}

// ---------------------------------------------------------------------------
// FPS. One block per cloud, 256 threads, 16 points/thread in registers.
// (Reverted to the measured-best 638us structure: 4 waves; 512-thr variant
//  regressed to 757us -- barrier skew + bigger tail beat the issue savings.)
// ---------------------------------------------------------------------------
__device__ __forceinline__ f32x2 pk_sub(f32x2 a, f32x2 b) {
  f32x2 d;
  asm("v_pk_add_f32 %0, %1, %2 neg_lo:[0,1] neg_hi:[0,1]" : "=v"(d) : "v"(a), "v"(b));
  return d;
}
__device__ __forceinline__ f32x2 pk_mul(f32x2 a, f32x2 b) {
  f32x2 d;
  asm("v_pk_mul_f32 %0, %1, %2" : "=v"(d) : "v"(a), "v"(b));
  return d;
}
__device__ __forceinline__ f32x2 pk_add(f32x2 a, f32x2 b) {
  f32x2 d;
  asm("v_pk_add_f32 %0, %1, %2" : "=v"(d) : "v"(a), "v"(b));
  return d;
}

template <int CTRL>
__device__ __forceinline__ unsigned long long dpp_max_u64(unsigned long long k) {
  unsigned lo = (unsigned)__builtin_amdgcn_update_dpp(0, (int)(unsigned)k,         CTRL, 0xF, 0xF, true);
  unsigned hi = (unsigned)__builtin_amdgcn_update_dpp(0, (int)(unsigned)(k >> 32), CTRL, 0xF, 0xF, true);
  unsigned long long p = ((unsigned long long)hi << 32) | lo;
  return p > k ? p : k;
}

__global__ __launch_bounds__(256) void fps_kernel(const float* __restrict__ pos,
                                                  int* __restrict__ fps_idx,
                                                  float* __restrict__ pos_s) {
  __shared__ alignas(16) float4 pp[N_];
  __shared__ alignas(32) unsigned long long sw[2][4];

  const int b   = blockIdx.x;
  const int tid = threadIdx.x;
  const float* pb = pos + (size_t)b * N_ * 3;
  for (int i = tid; i < N_; i += 256)
    pp[i] = make_float4(pb[3 * i], pb[3 * i + 1], pb[3 * i + 2], 0.0f);
  __syncthreads();

  f32x2 X2[8], Y2[8], Z2[8];
  float D[16];
  unsigned lo16[16];
  const unsigned ntid = ~(unsigned)tid;
#pragma unroll
  for (int j = 0; j < 8; j++) {
    float4 p0 = pp[tid + ((2 * j) << 8)];
    float4 p1 = pp[tid + ((2 * j + 1) << 8)];
    X2[j][0] = p0.x; X2[j][1] = p1.x;
    Y2[j][0] = p0.y; Y2[j][1] = p1.y;
    Z2[j][0] = p0.z; Z2[j][1] = p1.z;
    D[2 * j] = 1e30f; D[2 * j + 1] = 1e30f;
    lo16[2 * j]     = ntid - (unsigned)((2 * j) << 8);
    lo16[2 * j + 1] = ntid - (unsigned)((2 * j + 1) << 8);
  }

  float4 q = pp[0];
  if (tid == 0) {
    fps_idx[b * M_] = 0;
    float* o = pos_s + (size_t)b * M_ * 3;
    o[0] = q.x; o[1] = q.y; o[2] = q.z;
  }

  for (int i = 1; i < M_; i++) {
    f32x2 qx; qx[0] = q.x; qx[1] = q.x;
    f32x2 qy; qy[0] = q.y; qy[1] = q.y;
    f32x2 qz; qz[0] = q.z; qz[1] = q.z;
    unsigned long long key[16];
#pragma unroll
    for (int j = 0; j < 8; j++) {
      f32x2 dx = pk_sub(X2[j], qx);
      f32x2 dy = pk_sub(Y2[j], qy);
      f32x2 dz = pk_sub(Z2[j], qz);
      f32x2 t0 = pk_mul(dx, dx);
      f32x2 t1 = pk_mul(dy, dy);
      f32x2 s  = pk_add(t0, t1);
      f32x2 t2 = pk_mul(dz, dz);
      f32x2 d2 = pk_add(s, t2);
      D[2 * j]     = fminf(D[2 * j],     d2[0]);
      D[2 * j + 1] = fminf(D[2 * j + 1], d2[1]);
      key[2 * j]     = ((unsigned long long)__float_as_uint(D[2 * j])     << 32) | lo16[2 * j];
      key[2 * j + 1] = ((unsigned long long)__float_as_uint(D[2 * j + 1]) << 32) | lo16[2 * j + 1];
    }
#pragma unroll
    for (int s = 8; s > 0; s >>= 1)
#pragma unroll
      for (int k = 0; k < s; k++)
        if (key[k + s] > key[k]) key[k] = key[k + s];
    unsigned long long kk = key[0];

    // full-wave VALU-pipe reduce: lane 63 ends with the wave max
    kk = dpp_max_u64<0xB1>(kk);    // quad_perm xor1
    kk = dpp_max_u64<0x4E>(kk);    // quad_perm xor2
    kk = dpp_max_u64<0x141>(kk);   // row_half_mirror (xor4)
    kk = dpp_max_u64<0x140>(kk);   // row_mirror (xor8)
    kk = dpp_max_u64<0x142>(kk);   // row_bcast15
    kk = dpp_max_u64<0x143>(kk);   // row_bcast31

    const int par = i & 1;
    if ((tid & 63) == 63) sw[par][tid >> 6] = kk;
    __syncthreads();

    const ulonglong2 v01 = *(const ulonglong2*)&sw[par][0];
    const ulonglong2 v23 = *(const ulonglong2*)&sw[par][2];
    // load all 4 candidate positions in parallel with the compare chain
    const int c0 = (int)(~(unsigned)v01.x), c1 = (int)(~(unsigned)v01.y);
    const int c2 = (int)(~(unsigned)v23.x), c3 = (int)(~(unsigned)v23.y);
    float4 q0 = pp[c0], q1 = pp[c1], q2 = pp[c2], q3 = pp[c3];
    unsigned long long k01, k23; float4 q01, q23; int i01, i23;
    if (v01.y > v01.x) { k01 = v01.y; q01 = q1; i01 = c1; }
    else               { k01 = v01.x; q01 = q0; i01 = c0; }
    if (v23.y > v23.x) { k23 = v23.y; q23 = q3; i23 = c3; }
    else               { k23 = v23.x; q23 = q2; i23 = c2; }
    int cur;
    if (k23 > k01) { q = q23; cur = i23; }
    else           { q = q01; cur = i01; }

    if (tid == 0) {
      fps_idx[b * M_ + i] = cur;
      float* o = pos_s + ((size_t)b * M_ + i) * 3;
      o[0] = q.x; o[1] = q.y; o[2] = q.z;
    }
  }
}

// ---------------------------------------------------------------------------
// kNN (seeded): Pass A distances + lane-min; bitonic-sort lane-mins; seed the
// sorted top-32 (threshold T0 = 32nd-smallest lane-min >= true 32nd key);
// Pass B scans skipping seeded keys. Exact top_k semantics via u64 keys.
// ---------------------------------------------------------------------------
__global__ __launch_bounds__(256) void knn_kernel(const float* __restrict__ pos,
                                                  const int* __restrict__ fps_idx,
                                                  unsigned short* __restrict__ nbr) {
  __shared__ alignas(16) float4 pp[N_];
  const int b    = blockIdx.x >> 8;
  const int mset = blockIdx.x & 255;
  const int tid  = threadIdx.x;
  const int w    = tid >> 6;
  const int lane = tid & 63;

  const float* pb = pos + (size_t)b * N_ * 3;
  for (int i = tid; i < N_; i += 256)
    pp[i] = make_float4(pb[3 * i], pb[3 * i + 1], pb[3 * i + 2], 0.0f);
  __syncthreads();

  const int m  = mset * 4 + w;
  const int ci = fps_idx[b * M_ + m];
  const float4 c = pp[ci];

  // ---- Pass A: distances + lane-min key ----
  float d2v[64];
  unsigned long long kmin = ~0ull;
#pragma unroll
  for (int t = 0; t < 64; t++) {
    const int j = t * 64 + lane;
    const float4 p = pp[j];
    float dx = __fsub_rn(p.x, c.x);
    float dy = __fsub_rn(p.y, c.y);
    float dz = __fsub_rn(p.z, c.z);
    float d  = __fadd_rn(__fadd_rn(__fmul_rn(dx, dx), __fmul_rn(dy, dy)),
                         __fmul_rn(dz, dz));
    d2v[t] = d;
    const unsigned long long k64 =
        ((unsigned long long)__float_as_uint(d) << 32) | (unsigned int)j;
    if (k64 < kmin) kmin = k64;
  }

  // ---- bitonic sort of the 64 lane-min keys (ascending across lanes) ----
  unsigned long long sk = kmin;
#pragma unroll
  for (int size = 2; size <= 64; size <<= 1) {
#pragma unroll
    for (int stride = size >> 1; stride > 0; stride >>= 1) {
      const unsigned long long other = __shfl_xor(sk, stride);
      const bool up      = ((lane & size) == 0);
      const bool lowhalf = ((lane & stride) == 0);
      const bool takeMin = (up == lowhalf);
      const bool sw      = takeMin ? (other < sk) : (other > sk);
      if (sw) sk = other;
    }
  }
  const unsigned long long T0 = __shfl(sk, 31);
  const bool seeded = (kmin <= T0);

  // seed list: lanes 0..31 hold the 32 smallest lane-min keys, sorted
  unsigned long long rkey = (lane < 32) ? sk : ~0ull;
  unsigned long long wk   = T0;   // == current list max

  // ---- Pass B: scan, skipping seeded keys ----
#pragma unroll
  for (int t = 0; t < 64; t++) {
    const int j = t * 64 + lane;
    const unsigned long long k64 =
        ((unsigned long long)__float_as_uint(d2v[t]) << 32) | (unsigned int)j;
    const bool skip = seeded && (k64 == kmin);
    unsigned long long mask = __ballot((k64 < wk) && !skip);
    if (mask) {
      while (mask) {
        const int src = __ffsll((unsigned long long)mask) - 1;
        mask &= mask - 1;
        const unsigned long long cand = __shfl(k64, src);
        const int pos_i = (int)__popcll(__ballot(rkey < cand));  // >=32 -> no-op
        const unsigned long long sh = __shfl_up(rkey, 1);
        if (lane < 32) {
          if (lane == pos_i)      rkey = cand;
          else if (lane > pos_i)  rkey = sh;
        }
      }
      wk = __shfl(rkey, 31);
    }
  }
  if (lane < 32)
    nbr[(size_t)(b * M_ + m) * K_ + lane] = (unsigned short)(rkey & 0xFFFFull);
}

// ---------------------------------------------------------------------------
// Fused gather + MLP + maxpool. Block = 4 waves, 4 centroids, 128 rows.
// NEW SPLIT: wave w owns an output COLUMN slice for ALL 128 rows (L1/L2:
// 32 cols = 2 n-tiles; L3: 64 cols = 4 n-tiles in 2 passes). Each weight
// fragment is now reused across 8 row-tiles instead of 2 -> 4x less weight
// traffic from L2 (120KB/block vs 480KB/block).
// ---------------------------------------------------------------------------
#define AST 136

__global__ __launch_bounds__(256) void mlp_kernel(
    const float* __restrict__ x, const float* __restrict__ pos,
    const float* __restrict__ b1, const float* __restrict__ b2,
    const float* __restrict__ b3,
    const unsigned short* __restrict__ nbr,
    const __bf16* __restrict__ w1t, const __bf16* __restrict__ w2t,
    const __bf16* __restrict__ w3t,
    float* __restrict__ out, const float* __restrict__ pos_s) {
  __shared__ alignas(16) __bf16 bufA[128 * AST];   // msg (k=0..95), later act2 (k=0..127)
  __shared__ alignas(16) __bf16 bufB[128 * AST];   // act1

  const int b    = blockIdx.x >> 8;
  const int mset = blockIdx.x & 255;
  const int w    = threadIdx.x >> 6;
  const int lane = threadIdx.x & 63;
  const int m    = mset * 4 + w;    // centroid gathered by this wave

  // ---- gather: wave w fills rows [32w, 32w+32) with centroid m's neighbors ----
  {
    const int rl   = lane >> 1;      // neighbor slot 0..31
    const int half = lane & 1;
    const int r    = w * 32 + rl;
    const int nj   = (int)nbr[(size_t)(b * M_ + m) * K_ + rl];
    const float4* xr = (const float4*)(x + ((size_t)(b * N_ + nj)) * 64 + half * 32);
    __bf16* dst = &bufA[r * AST + half * 32];
#pragma unroll
    for (int t = 0; t < 8; t++) {
      float4 v = xr[t];
      bf16x4 u;
      u[0] = (__bf16)v.x; u[1] = (__bf16)v.y; u[2] = (__bf16)v.z; u[3] = (__bf16)v.w;
      *(bf16x4*)(dst + t * 4) = u;
    }
    bf16x8 z;
#pragma unroll
    for (int q2 = 0; q2 < 8; q2++) z[q2] = (__bf16)0.0f;
    if (half == 0) {
      const float* pj = pos + ((size_t)(b * N_ + nj)) * 3;
      const float* ps = pos_s + ((size_t)(b * M_ + m)) * 3;
      bf16x8 u = z;
      u[0] = (__bf16)(pj[0] - ps[0]);
      u[1] = (__bf16)(pj[1] - ps[1]);
      u[2] = (__bf16)(pj[2] - ps[2]);
      *(bf16x8*)&bufA[r * AST + 64] = u;
      *(bf16x8*)&bufA[r * AST + 72] = z;
    } else {
      *(bf16x8*)&bufA[r * AST + 80] = z;
      *(bf16x8*)&bufA[r * AST + 88] = z;
    }
  }
  __syncthreads();

  const int lrow = lane & 15;
  const int lk8  = (lane >> 4) << 3;   // k offset within 32-step
  const int orow = (lane >> 4) << 2;   // D row base within tile

  // ---- layer 1: msg(96) @ W1 -> relu -> bufB. Wave w: cols [32w,32w+32) ----
  {
    f32x4 acc[8][2];
#pragma unroll
    for (int n = 0; n < 2; n++) {
      const float bv = b1[(2 * w + n) * 16 + lrow];
      f32x4 a = {bv, bv, bv, bv};
#pragma unroll
      for (int rt = 0; rt < 8; rt++) acc[rt][n] = a;
    }
#pragma unroll
    for (int s = 0; s < 3; s++) {
      bf16x8 a[8];
#pragma unroll
      for (int rt = 0; rt < 8; rt++)
        a[rt] = *(const bf16x8*)&bufA[(rt * 16 + lrow) * AST + s * 32 + lk8];
#pragma unroll
      for (int n = 0; n < 2; n++) {
        bf16x8 bb = *(const bf16x8*)&w1t[((2 * w + n) * 16 + lrow) * 96 + s * 32 + lk8];
#pragma unroll
        for (int rt = 0; rt < 8; rt++)
          acc[rt][n] = __builtin_amdgcn_mfma_f32_16x16x32_bf16(a[rt], bb, acc[rt][n], 0, 0, 0);
      }
    }
    __syncthreads();   // all reads of bufA done before bufB write aliases? (bufB separate; barrier orders reads of bufA for L2's writers)
#pragma unroll
    for (int n = 0; n < 2; n++)
#pragma unroll
      for (int rt = 0; rt < 8; rt++)
#pragma unroll
        for (int j = 0; j < 4; j++)
          bufB[(rt * 16 + orow + j) * AST + (2 * w + n) * 16 + lrow] =
              (__bf16)fmaxf(acc[rt][n][j], 0.0f);
  }
  __syncthreads();

  // ---- layer 2: bufB(128) @ W2 -> relu -> bufA. Wave w: cols [32w,32w+32) ----
  {
    f32x4 acc[8][2];
#pragma unroll
    for (int n = 0; n < 2; n++) {
      const float bv = b2[(2 * w + n) * 16 + lrow];
      f32x4 a = {bv, bv, bv, bv};
#pragma unroll
      for (int rt = 0; rt < 8; rt++) acc[rt][n] = a;
    }
#pragma unroll
    for (int s = 0; s < 4; s++) {
      bf16x8 a[8];
#pragma unroll
      for (int rt = 0; rt < 8; rt++)
        a[rt] = *(const bf16x8*)&bufB[(rt * 16 + lrow) * AST + s * 32 + lk8];
#pragma unroll
      for (int n = 0; n < 2; n++) {
        bf16x8 bb = *(const bf16x8*)&w2t[((2 * w + n) * 16 + lrow) * 128 + s * 32 + lk8];
#pragma unroll
        for (int rt = 0; rt < 8; rt++)
          acc[rt][n] = __builtin_amdgcn_mfma_f32_16x16x32_bf16(a[rt], bb, acc[rt][n], 0, 0, 0);
      }
    }
    __syncthreads();   // bufA msg reads (none remain) / order bufA writes after L1 reads done
#pragma unroll
    for (int n = 0; n < 2; n++)
#pragma unroll
      for (int rt = 0; rt < 8; rt++)
#pragma unroll
        for (int j = 0; j < 4; j++)
          bufA[(rt * 16 + orow + j) * AST + (2 * w + n) * 16 + lrow] =
              (__bf16)fmaxf(acc[rt][n][j], 0.0f);
  }
  __syncthreads();

  // ---- layer 3 + maxpool. Wave w: cols [64w, 64w+64) in two 32-col passes ----
#pragma unroll
  for (int np = 0; np < 2; np++) {
    f32x4 acc[8][2];
#pragma unroll
    for (int n = 0; n < 2; n++) {
      const float bv = b3[(4 * w + 2 * np + n) * 16 + lrow];
      f32x4 a = {bv, bv, bv, bv};
#pragma unroll
      for (int rt = 0; rt < 8; rt++) acc[rt][n] = a;
    }
#pragma unroll
    for (int s = 0; s < 4; s++) {
      bf16x8 a[8];
#pragma unroll
      for (int rt = 0; rt < 8; rt++)
        a[rt] = *(const bf16x8*)&bufA[(rt * 16 + lrow) * AST + s * 32 + lk8];
#pragma unroll
      for (int n = 0; n < 2; n++) {
        bf16x8 bb = *(const bf16x8*)&w3t[((4 * w + 2 * np + n) * 16 + lrow) * 128 + s * 32 + lk8];
#pragma unroll
        for (int rt = 0; rt < 8; rt++)
          acc[rt][n] = __builtin_amdgcn_mfma_f32_16x16x32_bf16(a[rt], bb, acc[rt][n], 0, 0, 0);
      }
    }
    // pool: centroid c <- rows [32c, 32c+32) = row-tiles 2c, 2c+1
#pragma unroll
    for (int ccc = 0; ccc < 4; ccc++) {
#pragma unroll
      for (int n = 0; n < 2; n++) {
        f32x4 a0 = acc[2 * ccc][n], a1 = acc[2 * ccc + 1][n];
        float v = fmaxf(fmaxf(fmaxf(a0[0], a0[1]), fmaxf(a0[2], a0[3])),
                        fmaxf(fmaxf(a1[0], a1[1]), fmaxf(a1[2], a1[3])));
        v = fmaxf(v, __shfl_xor(v, 16));
        v = fmaxf(v, __shfl_xor(v, 32));
        v = fmaxf(v, 0.0f);   // relu commutes with max
        if (lane < 16)
          out[((size_t)(b * M_ + mset * 4 + ccc)) * 256 + (4 * w + 2 * np + n) * 16 + lane] = v;
      }
    }
  }
}

// ---------------------------------------------------------------------------
extern "C" void kernel_launch(void* const* d_in, const int* in_sizes, int n_in,
                              void* d_out, int out_size, void* d_ws, size_t ws_size,
                              hipStream_t stream) {
  const float* x   = (const float*)d_in[0];
  const float* pos = (const float*)d_in[1];
  const float* W1  = (const float*)d_in[2];
  const float* b1  = (const float*)d_in[3];
  const float* W2  = (const float*)d_in[4];
  const float* b2  = (const float*)d_in[5];
  const float* W3  = (const float*)d_in[6];
  const float* b3  = (const float*)d_in[7];

  float* out   = (float*)d_out;
  float* pos_s = out + (size_t)B_ * M_ * 256;

  char* ws = (char*)d_ws;
  int*            fps_idx = (int*)ws;                              // 65536 B
  unsigned short* nbr     = (unsigned short*)(ws + 65536);         // 1048576 B
  __bf16*         w1t     = (__bf16*)(ws + 1114112);               // 24576 B
  __bf16*         w2t     = (__bf16*)(ws + 1138688);               // 32768 B
  __bf16*         w3t     = (__bf16*)(ws + 1171456);               // 65536 B

  prep_weights<<<dim3(128), dim3(256), 0, stream>>>(W1, W2, W3, w1t, w2t, w3t);
  fps_kernel<<<dim3(B_), dim3(256), 0, stream>>>(pos, fps_idx, pos_s);
  knn_kernel<<<dim3(B_ * (M_ / 4)), dim3(256), 0, stream>>>(pos, fps_idx, nbr);
  mlp_kernel<<<dim3(B_ * (M_ / 4)), dim3(256), 0, stream>>>(
      x, pos, b1, b2, b3, nbr, w1t, w2t, w3t, out, pos_s);
}

// Round 6
// 807.119 us; speedup vs baseline: 2.0729x; 1.0068x over previous
//
#include <hip/hip_runtime.h>

// SAModule (PointNet++): FPS -> kNN(32) -> [x||rel] MLP(67->128->128->256) -> max over K.
// B=16, N=4096, C=64, M=1024, K=32.
// R5: single fused kernel. Blocks 0..15 = FPS producers (setprio 3, publish
// progress[b] every 8 iters with agent-release). Blocks 16..495 = persistent
// workers pulling items (b,mset) from an atomic counter, gating on progress
// (agent-acquire + s_sleep), then kNN + col-split MLP for 4 centroids with
// nbr kept in registers. knn+mlp hide entirely under FPS's 638us shadow.

#define B_    16
#define N_    4096
#define M_    1024
#define AST   136
#define NWORK 480
#define NITEM (256 * 16)   // items ordered mset-major: it = mset*16 + b

typedef __bf16 bf16x8 __attribute__((ext_vector_type(8)));
typedef __bf16 bf16x4 __attribute__((ext_vector_type(4)));
typedef float  f32x4  __attribute__((ext_vector_type(4)));
typedef float  f32x2  __attribute__((ext_vector_type(2)));

// ---------------------------------------------------------------------------
// Weight prep: transpose + cast to bf16, pad W1 K-dim 67->96 with zeros.
// ---------------------------------------------------------------------------
__global__ __launch_bounds__(256) void prep_weights(
    const float* __restrict__ W1, const float* __restrict__ W2,
    const float* __restrict__ W3,
    __bf16* __restrict__ w1t, __bf16* __restrict__ w2t, __bf16* __restrict__ w3t) {
  const int t = blockIdx.x * 256 + threadIdx.x;   // 0..32767
  if (t < 128 * 96) {
    const int n = t / 96, k = t % 96;
    w1t[t] = (k < 67) ? (__bf16)W1[k * 128 + n] : (__bf16)0.0f;
  }
  if (t < 128 * 128) {
    const int n = t >> 7, k = t & 127;
    w2t[t] = (__bf16)W2[k * 128 + n];
  }
  {
    const int n = t >> 7, k = t & 127;   // t < 256*128 always
    w3t[t] = (__bf16)W3[k * 256 + n];
  }
}

// ---------------------------------------------------------------------------
__device__ __forceinline__ f32x2 pk_sub(f32x2 a, f32x2 b) {
  f32x2 d;
  asm("v_pk_add_f32 %0, %1, %2 neg_lo:[0,1] neg_hi:[0,1]" : "=v"(d) : "v"(a), "v"(b));
  return d;
}
__device__ __forceinline__ f32x2 pk_mul(f32x2 a, f32x2 b) {
  f32x2 d;
  asm("v_pk_mul_f32 %0, %1, %2" : "=v"(d) : "v"(a), "v"(b));
  return d;
}
__device__ __forceinline__ f32x2 pk_add(f32x2 a, f32x2 b) {
  f32x2 d;
  asm("v_pk_add_f32 %0, %1, %2" : "=v"(d) : "v"(a), "v"(b));
  return d;
}

template <int CTRL>
__device__ __forceinline__ unsigned long long dpp_max_u64(unsigned long long k) {
  unsigned lo = (unsigned)__builtin_amdgcn_update_dpp(0, (int)(unsigned)k,         CTRL, 0xF, 0xF, true);
  unsigned hi = (unsigned)__builtin_amdgcn_update_dpp(0, (int)(unsigned)(k >> 32), CTRL, 0xF, 0xF, true);
  unsigned long long p = ((unsigned long long)hi << 32) | lo;
  return p > k ? p : k;
}

union ShU {
  struct { float4 pp[N_]; unsigned long long sw[2][4]; } f;   // fps / knn view
  struct { __bf16 A[128 * AST]; __bf16 Bv[128 * AST]; } g;    // mlp view
};

// ---------------------------------------------------------------------------
__global__ __launch_bounds__(256) void fused_kernel(
    const float* __restrict__ pos, const float* __restrict__ x,
    const float* __restrict__ b1, const float* __restrict__ b2,
    const float* __restrict__ b3,
    const __bf16* __restrict__ w1t, const __bf16* __restrict__ w2t,
    const __bf16* __restrict__ w3t,
    int* __restrict__ fps_idx, int* __restrict__ progress, int* __restrict__ ctr,
    float* __restrict__ out, float* __restrict__ pos_s) {
  __shared__ alignas(16) ShU sh;
  __shared__ int sh_item;
  const int tid = threadIdx.x;

  if (blockIdx.x < B_) {
    // ================= FPS producer (R4's verified 638us body) =================
    __builtin_amdgcn_s_setprio(3);   // starve-proof vs co-resident prio-0 workers
    const int b = blockIdx.x;
    const float* pb = pos + (size_t)b * N_ * 3;
    for (int i = tid; i < N_; i += 256)
      sh.f.pp[i] = make_float4(pb[3 * i], pb[3 * i + 1], pb[3 * i + 2], 0.0f);
    __syncthreads();

    f32x2 X2[8], Y2[8], Z2[8];
    float D[16];
    unsigned lo16[16];
    const unsigned ntid = ~(unsigned)tid;
#pragma unroll
    for (int j = 0; j < 8; j++) {
      float4 p0 = sh.f.pp[tid + ((2 * j) << 8)];
      float4 p1 = sh.f.pp[tid + ((2 * j + 1) << 8)];
      X2[j][0] = p0.x; X2[j][1] = p1.x;
      Y2[j][0] = p0.y; Y2[j][1] = p1.y;
      Z2[j][0] = p0.z; Z2[j][1] = p1.z;
      D[2 * j] = 1e30f; D[2 * j + 1] = 1e30f;
      lo16[2 * j]     = ntid - (unsigned)((2 * j) << 8);
      lo16[2 * j + 1] = ntid - (unsigned)((2 * j + 1) << 8);
    }

    float4 q = sh.f.pp[0];
    if (tid == 0) {
      fps_idx[b * M_] = 0;
      float* o = pos_s + (size_t)b * M_ * 3;
      o[0] = q.x; o[1] = q.y; o[2] = q.z;
    }

    for (int i = 1; i < M_; i++) {
      f32x2 qx; qx[0] = q.x; qx[1] = q.x;
      f32x2 qy; qy[0] = q.y; qy[1] = q.y;
      f32x2 qz; qz[0] = q.z; qz[1] = q.z;
      unsigned long long key[16];
#pragma unroll
      for (int j = 0; j < 8; j++) {
        f32x2 dx = pk_sub(X2[j], qx);
        f32x2 dy = pk_sub(Y2[j], qy);
        f32x2 dz = pk_sub(Z2[j], qz);
        f32x2 t0 = pk_mul(dx, dx);
        f32x2 t1 = pk_mul(dy, dy);
        f32x2 s  = pk_add(t0, t1);
        f32x2 t2 = pk_mul(dz, dz);
        f32x2 d2 = pk_add(s, t2);
        D[2 * j]     = fminf(D[2 * j],     d2[0]);
        D[2 * j + 1] = fminf(D[2 * j + 1], d2[1]);
        key[2 * j]     = ((unsigned long long)__float_as_uint(D[2 * j])     << 32) | lo16[2 * j];
        key[2 * j + 1] = ((unsigned long long)__float_as_uint(D[2 * j + 1]) << 32) | lo16[2 * j + 1];
      }
#pragma unroll
      for (int s = 8; s > 0; s >>= 1)
#pragma unroll
        for (int k = 0; k < s; k++)
          if (key[k + s] > key[k]) key[k] = key[k + s];
      unsigned long long kk = key[0];

      kk = dpp_max_u64<0xB1>(kk);    // quad_perm xor1
      kk = dpp_max_u64<0x4E>(kk);    // quad_perm xor2
      kk = dpp_max_u64<0x141>(kk);   // row_half_mirror (xor4)
      kk = dpp_max_u64<0x140>(kk);   // row_mirror (xor8)
      kk = dpp_max_u64<0x142>(kk);   // row_bcast15
      kk = dpp_max_u64<0x143>(kk);   // row_bcast31

      const int par = i & 1;
      if ((tid & 63) == 63) sh.f.sw[par][tid >> 6] = kk;
      __syncthreads();

      const ulonglong2 v01 = *(const ulonglong2*)&sh.f.sw[par][0];
      const ulonglong2 v23 = *(const ulonglong2*)&sh.f.sw[par][2];
      const int c0 = (int)(~(unsigned)v01.x), c1 = (int)(~(unsigned)v01.y);
      const int c2 = (int)(~(unsigned)v23.x), c3 = (int)(~(unsigned)v23.y);
      float4 q0 = sh.f.pp[c0], q1 = sh.f.pp[c1], q2 = sh.f.pp[c2], q3 = sh.f.pp[c3];
      unsigned long long k01, k23; float4 q01, q23; int i01, i23;
      if (v01.y > v01.x) { k01 = v01.y; q01 = q1; i01 = c1; }
      else               { k01 = v01.x; q01 = q0; i01 = c0; }
      if (v23.y > v23.x) { k23 = v23.y; q23 = q3; i23 = c3; }
      else               { k23 = v23.x; q23 = q2; i23 = c2; }
      int cur;
      if (k23 > k01) { q = q23; cur = i23; }
      else           { q = q01; cur = i01; }

      if (tid == 0) {
        fps_idx[b * M_ + i] = cur;
        float* o = pos_s + ((size_t)b * M_ + i) * 3;
        o[0] = q.x; o[1] = q.y; o[2] = q.z;
        if (((i + 1) & 7) == 0)
          __hip_atomic_store(progress + b, i + 1, __ATOMIC_RELEASE,
                             __HIP_MEMORY_SCOPE_AGENT);
      }
    }
    return;
  }

  // ================= persistent worker: kNN + MLP per item =================
  const int w    = tid >> 6;
  const int lane = tid & 63;

  for (;;) {
    if (tid == 0) sh_item = atomicAdd(ctr, 1);
    __syncthreads();
    const int it = sh_item;
    if (it >= NITEM) return;
    const int b    = it & 15;
    const int mset = it >> 4;
    const int m    = mset * 4 + w;

    __syncthreads();   // previous item's LDS reads complete before restage
    {
      const float* pb = pos + (size_t)b * N_ * 3;
      for (int i = tid; i < N_; i += 256)
        sh.f.pp[i] = make_float4(pb[3 * i], pb[3 * i + 1], pb[3 * i + 2], 0.0f);
    }
    if (tid == 0) {
      const int need = (mset + 1) * 4;
      while (__hip_atomic_load(progress + b, __ATOMIC_ACQUIRE,
                               __HIP_MEMORY_SCOPE_AGENT) < need)
        __builtin_amdgcn_s_sleep(16);
    }
    __syncthreads();   // gate passed + staging visible

    int ci0 = 0;
    if (lane == 0)
      ci0 = __hip_atomic_load(fps_idx + b * M_ + m, __ATOMIC_RELAXED,
                              __HIP_MEMORY_SCOPE_AGENT);
    const int ci = __shfl(ci0, 0);
    const float4 c = sh.f.pp[ci];

    // ---- kNN pass A: distances + lane-min key ----
    float d2v[64];
    unsigned long long kmin = ~0ull;
#pragma unroll
    for (int t = 0; t < 64; t++) {
      const int j = t * 64 + lane;
      const float4 p = sh.f.pp[j];
      float dx = __fsub_rn(p.x, c.x);
      float dy = __fsub_rn(p.y, c.y);
      float dz = __fsub_rn(p.z, c.z);
      float d  = __fadd_rn(__fadd_rn(__fmul_rn(dx, dx), __fmul_rn(dy, dy)),
                           __fmul_rn(dz, dz));
      d2v[t] = d;
      const unsigned long long k64 =
          ((unsigned long long)__float_as_uint(d) << 32) | (unsigned int)j;
      if (k64 < kmin) kmin = k64;
    }

    // ---- bitonic sort of lane-min keys; seed top-32; threshold T0 ----
    unsigned long long sk = kmin;
#pragma unroll
    for (int size = 2; size <= 64; size <<= 1) {
#pragma unroll
      for (int stride = size >> 1; stride > 0; stride >>= 1) {
        const unsigned long long other = __shfl_xor(sk, stride);
        const bool up      = ((lane & size) == 0);
        const bool lowhalf = ((lane & stride) == 0);
        const bool takeMin = (up == lowhalf);
        const bool swp     = takeMin ? (other < sk) : (other > sk);
        if (swp) sk = other;
      }
    }
    const unsigned long long T0 = __shfl(sk, 31);
    const bool seeded = (kmin <= T0);

    unsigned long long rkey = (lane < 32) ? sk : ~0ull;
    unsigned long long wk   = T0;

    // ---- pass B: scan, skipping seeded keys ----
#pragma unroll
    for (int t = 0; t < 64; t++) {
      const int j = t * 64 + lane;
      const unsigned long long k64 =
          ((unsigned long long)__float_as_uint(d2v[t]) << 32) | (unsigned int)j;
      const bool skip = seeded && (k64 == kmin);
      unsigned long long mask = __ballot((k64 < wk) && !skip);
      if (mask) {
        while (mask) {
          const int src = __ffsll((unsigned long long)mask) - 1;
          mask &= mask - 1;
          const unsigned long long cand = __shfl(k64, src);
          const int pos_i = (int)__popcll(__ballot(rkey < cand));  // >=32 -> no-op
          const unsigned long long sh_ = __shfl_up(rkey, 1);
          if (lane < 32) {
            if (lane == pos_i)      rkey = cand;
            else if (lane > pos_i)  rkey = sh_;
          }
        }
        wk = __shfl(rkey, 31);
      }
    }
    const int njl = (int)(rkey & 0xFFFFull);   // valid in lanes 0..31
    __syncthreads();   // all pp reads done before mlp buffers alias it

    // ---- gather: wave w fills rows [32w,32w+32) for its centroid ----
    {
      const int rl   = lane >> 1;
      const int half = lane & 1;
      const int r    = w * 32 + rl;
      const int nj   = __shfl(njl, rl);
      const float4* xr = (const float4*)(x + ((size_t)(b * N_ + nj)) * 64 + half * 32);
      __bf16* dst = &sh.g.A[r * AST + half * 32];
#pragma unroll
      for (int t = 0; t < 8; t++) {
        float4 v = xr[t];
        bf16x4 u;
        u[0] = (__bf16)v.x; u[1] = (__bf16)v.y; u[2] = (__bf16)v.z; u[3] = (__bf16)v.w;
        *(bf16x4*)(dst + t * 4) = u;
      }
      bf16x8 z;
#pragma unroll
      for (int q2 = 0; q2 < 8; q2++) z[q2] = (__bf16)0.0f;
      if (half == 0) {
        const float* pj = pos + ((size_t)(b * N_ + nj)) * 3;
        bf16x8 u = z;
        u[0] = (__bf16)(pj[0] - c.x);
        u[1] = (__bf16)(pj[1] - c.y);
        u[2] = (__bf16)(pj[2] - c.z);
        *(bf16x8*)&sh.g.A[r * AST + 64] = u;
        *(bf16x8*)&sh.g.A[r * AST + 72] = z;
      } else {
        *(bf16x8*)&sh.g.A[r * AST + 80] = z;
        *(bf16x8*)&sh.g.A[r * AST + 88] = z;
      }
    }
    __syncthreads();

    const int lrow = lane & 15;
    const int lk8  = (lane >> 4) << 3;
    const int orow = (lane >> 4) << 2;

    // ---- L1: msg(96) @ W1 -> relu -> Bv. Wave w: cols [32w,32w+32) ----
    {
      f32x4 acc[8][2];
#pragma unroll
      for (int n = 0; n < 2; n++) {
        const float bv = b1[(2 * w + n) * 16 + lrow];
        f32x4 a = {bv, bv, bv, bv};
#pragma unroll
        for (int rt = 0; rt < 8; rt++) acc[rt][n] = a;
      }
#pragma unroll
      for (int s = 0; s < 3; s++) {
        bf16x8 a[8];
#pragma unroll
        for (int rt = 0; rt < 8; rt++)
          a[rt] = *(const bf16x8*)&sh.g.A[(rt * 16 + lrow) * AST + s * 32 + lk8];
#pragma unroll
        for (int n = 0; n < 2; n++) {
          bf16x8 bb = *(const bf16x8*)&w1t[((2 * w + n) * 16 + lrow) * 96 + s * 32 + lk8];
#pragma unroll
          for (int rt = 0; rt < 8; rt++)
            acc[rt][n] = __builtin_amdgcn_mfma_f32_16x16x32_bf16(a[rt], bb, acc[rt][n], 0, 0, 0);
        }
      }
      __syncthreads();
#pragma unroll
      for (int n = 0; n < 2; n++)
#pragma unroll
        for (int rt = 0; rt < 8; rt++)
#pragma unroll
          for (int j = 0; j < 4; j++)
            sh.g.Bv[(rt * 16 + orow + j) * AST + (2 * w + n) * 16 + lrow] =
                (__bf16)fmaxf(acc[rt][n][j], 0.0f);
    }
    __syncthreads();

    // ---- L2: Bv(128) @ W2 -> relu -> A ----
    {
      f32x4 acc[8][2];
#pragma unroll
      for (int n = 0; n < 2; n++) {
        const float bv = b2[(2 * w + n) * 16 + lrow];
        f32x4 a = {bv, bv, bv, bv};
#pragma unroll
        for (int rt = 0; rt < 8; rt++) acc[rt][n] = a;
      }
#pragma unroll
      for (int s = 0; s < 4; s++) {
        bf16x8 a[8];
#pragma unroll
        for (int rt = 0; rt < 8; rt++)
          a[rt] = *(const bf16x8*)&sh.g.Bv[(rt * 16 + lrow) * AST + s * 32 + lk8];
#pragma unroll
        for (int n = 0; n < 2; n++) {
          bf16x8 bb = *(const bf16x8*)&w2t[((2 * w + n) * 16 + lrow) * 128 + s * 32 + lk8];
#pragma unroll
          for (int rt = 0; rt < 8; rt++)
            acc[rt][n] = __builtin_amdgcn_mfma_f32_16x16x32_bf16(a[rt], bb, acc[rt][n], 0, 0, 0);
        }
      }
      __syncthreads();
#pragma unroll
      for (int n = 0; n < 2; n++)
#pragma unroll
        for (int rt = 0; rt < 8; rt++)
#pragma unroll
          for (int j = 0; j < 4; j++)
            sh.g.A[(rt * 16 + orow + j) * AST + (2 * w + n) * 16 + lrow] =
                (__bf16)fmaxf(acc[rt][n][j], 0.0f);
    }
    __syncthreads();

    // ---- L3 + maxpool. Wave w: cols [64w,64w+64) in two passes ----
#pragma unroll
    for (int np = 0; np < 2; np++) {
      f32x4 acc[8][2];
#pragma unroll
      for (int n = 0; n < 2; n++) {
        const float bv = b3[(4 * w + 2 * np + n) * 16 + lrow];
        f32x4 a = {bv, bv, bv, bv};
#pragma unroll
        for (int rt = 0; rt < 8; rt++) acc[rt][n] = a;
      }
#pragma unroll
      for (int s = 0; s < 4; s++) {
        bf16x8 a[8];
#pragma unroll
        for (int rt = 0; rt < 8; rt++)
          a[rt] = *(const bf16x8*)&sh.g.A[(rt * 16 + lrow) * AST + s * 32 + lk8];
#pragma unroll
        for (int n = 0; n < 2; n++) {
          bf16x8 bb = *(const bf16x8*)&w3t[((4 * w + 2 * np + n) * 16 + lrow) * 128 + s * 32 + lk8];
#pragma unroll
          for (int rt = 0; rt < 8; rt++)
            acc[rt][n] = __builtin_amdgcn_mfma_f32_16x16x32_bf16(a[rt], bb, acc[rt][n], 0, 0, 0);
        }
      }
#pragma unroll
      for (int ccc = 0; ccc < 4; ccc++) {
#pragma unroll
        for (int n = 0; n < 2; n++) {
          f32x4 a0 = acc[2 * ccc][n], a1 = acc[2 * ccc + 1][n];
          float v = fmaxf(fmaxf(fmaxf(a0[0], a0[1]), fmaxf(a0[2], a0[3])),
                          fmaxf(fmaxf(a1[0], a1[1]), fmaxf(a1[2], a1[3])));
          v = fmaxf(v, __shfl_xor(v, 16));
          v = fmaxf(v, __shfl_xor(v, 32));
          v = fmaxf(v, 0.0f);
          if (lane < 16)
            out[((size_t)(b * M_ + mset * 4 + ccc)) * 256 + (4 * w + 2 * np + n) * 16 + lane] = v;
        }
      }
    }
    // loop to next item
  }
}

// ---------------------------------------------------------------------------
extern "C" void kernel_launch(void* const* d_in, const int* in_sizes, int n_in,
                              void* d_out, int out_size, void* d_ws, size_t ws_size,
                              hipStream_t stream) {
  const float* x   = (const float*)d_in[0];
  const float* pos = (const float*)d_in[1];
  const float* W1  = (const float*)d_in[2];
  const float* b1  = (const float*)d_in[3];
  const float* W2  = (const float*)d_in[4];
  const float* b2  = (const float*)d_in[5];
  const float* W3  = (const float*)d_in[6];
  const float* b3  = (const float*)d_in[7];

  float* out   = (float*)d_out;
  float* pos_s = out + (size_t)B_ * M_ * 256;

  char* ws = (char*)d_ws;
  int*    fps_idx  = (int*)ws;                       // 65536 B
  int*    progress = (int*)(ws + 65536);             // 64 B
  int*    ctr      = (int*)(ws + 65600);             // 4 B
  __bf16* w1t      = (__bf16*)(ws + 65792);          // 24576 B
  __bf16* w2t      = (__bf16*)(ws + 90368);          // 32768 B
  __bf16* w3t      = (__bf16*)(ws + 123136);         // 65536 B

  hipMemsetAsync(ws + 65536, 0, 68, stream);         // progress[16] + ctr
  prep_weights<<<dim3(128), dim3(256), 0, stream>>>(W1, W2, W3, w1t, w2t, w3t);
  fused_kernel<<<dim3(B_ + NWORK), dim3(256), 0, stream>>>(
      pos, x, b1, b2, b3, w1t, w2t, w3t, fps_idx, progress, ctr, out, pos_s);
}

// Round 7
// 804.628 us; speedup vs baseline: 2.0793x; 1.0031x over previous
//
#include <hip/hip_runtime.h>

// SAModule (PointNet++): FPS -> kNN(32) -> [x||rel] MLP(67->128->128->256) -> max over K.
// B=16, N=4096, C=64, M=1024, K=32.
// R6: fused producer/consumer, grid = 256 = 16 FPS + 240 workers -> exactly
// 1 block/CU, so FPS blocks own their CUs (no co-resident LDS/issue/L1-inv
// interference; R5's 496-block layout slowed FPS 638->820us).

#define B_    16
#define N_    4096
#define M_    1024
#define AST   136
#define NWORK 240
#define NITEM (256 * 16)   // items ordered mset-major: it = mset*16 + b

typedef __bf16 bf16x8 __attribute__((ext_vector_type(8)));
typedef __bf16 bf16x4 __attribute__((ext_vector_type(4)));
typedef float  f32x4  __attribute__((ext_vector_type(4)));
typedef float  f32x2  __attribute__((ext_vector_type(2)));

// ---------------------------------------------------------------------------
// Weight prep: transpose + cast to bf16, pad W1 K-dim 67->96 with zeros.
// ---------------------------------------------------------------------------
__global__ __launch_bounds__(256) void prep_weights(
    const float* __restrict__ W1, const float* __restrict__ W2,
    const float* __restrict__ W3,
    __bf16* __restrict__ w1t, __bf16* __restrict__ w2t, __bf16* __restrict__ w3t) {
  const int t = blockIdx.x * 256 + threadIdx.x;   // 0..32767
  if (t < 128 * 96) {
    const int n = t / 96, k = t % 96;
    w1t[t] = (k < 67) ? (__bf16)W1[k * 128 + n] : (__bf16)0.0f;
  }
  if (t < 128 * 128) {
    const int n = t >> 7, k = t & 127;
    w2t[t] = (__bf16)W2[k * 128 + n];
  }
  {
    const int n = t >> 7, k = t & 127;   // t < 256*128 always
    w3t[t] = (__bf16)W3[k * 256 + n];
  }
}

// ---------------------------------------------------------------------------
__device__ __forceinline__ f32x2 pk_sub(f32x2 a, f32x2 b) {
  f32x2 d;
  asm("v_pk_add_f32 %0, %1, %2 neg_lo:[0,1] neg_hi:[0,1]" : "=v"(d) : "v"(a), "v"(b));
  return d;
}
__device__ __forceinline__ f32x2 pk_mul(f32x2 a, f32x2 b) {
  f32x2 d;
  asm("v_pk_mul_f32 %0, %1, %2" : "=v"(d) : "v"(a), "v"(b));
  return d;
}
__device__ __forceinline__ f32x2 pk_add(f32x2 a, f32x2 b) {
  f32x2 d;
  asm("v_pk_add_f32 %0, %1, %2" : "=v"(d) : "v"(a), "v"(b));
  return d;
}

template <int CTRL>
__device__ __forceinline__ unsigned long long dpp_max_u64(unsigned long long k) {
  unsigned lo = (unsigned)__builtin_amdgcn_update_dpp(0, (int)(unsigned)k,         CTRL, 0xF, 0xF, true);
  unsigned hi = (unsigned)__builtin_amdgcn_update_dpp(0, (int)(unsigned)(k >> 32), CTRL, 0xF, 0xF, true);
  unsigned long long p = ((unsigned long long)hi << 32) | lo;
  return p > k ? p : k;
}

union ShU {
  struct { float4 pp[N_]; unsigned long long sw[2][4]; } f;   // fps / knn view
  struct { __bf16 A[128 * AST]; __bf16 Bv[128 * AST]; } g;    // mlp view
};

// ---------------------------------------------------------------------------
__global__ __launch_bounds__(256) void fused_kernel(
    const float* __restrict__ pos, const float* __restrict__ x,
    const float* __restrict__ b1, const float* __restrict__ b2,
    const float* __restrict__ b3,
    const __bf16* __restrict__ w1t, const __bf16* __restrict__ w2t,
    const __bf16* __restrict__ w3t,
    int* __restrict__ fps_idx, int* __restrict__ progress, int* __restrict__ ctr,
    float* __restrict__ out, float* __restrict__ pos_s) {
  __shared__ alignas(16) ShU sh;
  __shared__ int sh_item;
  const int tid = threadIdx.x;

  if (blockIdx.x < B_) {
    // ================= FPS producer (R4's verified 638us body) =================
    __builtin_amdgcn_s_setprio(3);
    const int b = blockIdx.x;
    const float* pb = pos + (size_t)b * N_ * 3;
    for (int i = tid; i < N_; i += 256)
      sh.f.pp[i] = make_float4(pb[3 * i], pb[3 * i + 1], pb[3 * i + 2], 0.0f);
    __syncthreads();

    f32x2 X2[8], Y2[8], Z2[8];
    float D[16];
    unsigned lo16[16];
    const unsigned ntid = ~(unsigned)tid;
#pragma unroll
    for (int j = 0; j < 8; j++) {
      float4 p0 = sh.f.pp[tid + ((2 * j) << 8)];
      float4 p1 = sh.f.pp[tid + ((2 * j + 1) << 8)];
      X2[j][0] = p0.x; X2[j][1] = p1.x;
      Y2[j][0] = p0.y; Y2[j][1] = p1.y;
      Z2[j][0] = p0.z; Z2[j][1] = p1.z;
      D[2 * j] = 1e30f; D[2 * j + 1] = 1e30f;
      lo16[2 * j]     = ntid - (unsigned)((2 * j) << 8);
      lo16[2 * j + 1] = ntid - (unsigned)((2 * j + 1) << 8);
    }

    float4 q = sh.f.pp[0];
    if (tid == 0) {
      fps_idx[b * M_] = 0;
      float* o = pos_s + (size_t)b * M_ * 3;
      o[0] = q.x; o[1] = q.y; o[2] = q.z;
    }

    for (int i = 1; i < M_; i++) {
      f32x2 qx; qx[0] = q.x; qx[1] = q.x;
      f32x2 qy; qy[0] = q.y; qy[1] = q.y;
      f32x2 qz; qz[0] = q.z; qz[1] = q.z;
      unsigned long long key[16];
#pragma unroll
      for (int j = 0; j < 8; j++) {
        f32x2 dx = pk_sub(X2[j], qx);
        f32x2 dy = pk_sub(Y2[j], qy);
        f32x2 dz = pk_sub(Z2[j], qz);
        f32x2 t0 = pk_mul(dx, dx);
        f32x2 t1 = pk_mul(dy, dy);
        f32x2 s  = pk_add(t0, t1);
        f32x2 t2 = pk_mul(dz, dz);
        f32x2 d2 = pk_add(s, t2);
        D[2 * j]     = fminf(D[2 * j],     d2[0]);
        D[2 * j + 1] = fminf(D[2 * j + 1], d2[1]);
        key[2 * j]     = ((unsigned long long)__float_as_uint(D[2 * j])     << 32) | lo16[2 * j];
        key[2 * j + 1] = ((unsigned long long)__float_as_uint(D[2 * j + 1]) << 32) | lo16[2 * j + 1];
      }
#pragma unroll
      for (int s = 8; s > 0; s >>= 1)
#pragma unroll
        for (int k = 0; k < s; k++)
          if (key[k + s] > key[k]) key[k] = key[k + s];
      unsigned long long kk = key[0];

      kk = dpp_max_u64<0xB1>(kk);    // quad_perm xor1
      kk = dpp_max_u64<0x4E>(kk);    // quad_perm xor2
      kk = dpp_max_u64<0x141>(kk);   // row_half_mirror (xor4)
      kk = dpp_max_u64<0x140>(kk);   // row_mirror (xor8)
      kk = dpp_max_u64<0x142>(kk);   // row_bcast15
      kk = dpp_max_u64<0x143>(kk);   // row_bcast31

      const int par = i & 1;
      if ((tid & 63) == 63) sh.f.sw[par][tid >> 6] = kk;
      __syncthreads();

      const ulonglong2 v01 = *(const ulonglong2*)&sh.f.sw[par][0];
      const ulonglong2 v23 = *(const ulonglong2*)&sh.f.sw[par][2];
      const int c0 = (int)(~(unsigned)v01.x), c1 = (int)(~(unsigned)v01.y);
      const int c2 = (int)(~(unsigned)v23.x), c3 = (int)(~(unsigned)v23.y);
      float4 q0 = sh.f.pp[c0], q1 = sh.f.pp[c1], q2 = sh.f.pp[c2], q3 = sh.f.pp[c3];
      unsigned long long k01, k23; float4 q01, q23; int i01, i23;
      if (v01.y > v01.x) { k01 = v01.y; q01 = q1; i01 = c1; }
      else               { k01 = v01.x; q01 = q0; i01 = c0; }
      if (v23.y > v23.x) { k23 = v23.y; q23 = q3; i23 = c3; }
      else               { k23 = v23.x; q23 = q2; i23 = c2; }
      int cur;
      if (k23 > k01) { q = q23; cur = i23; }
      else           { q = q01; cur = i01; }

      if (tid == 0) {
        fps_idx[b * M_ + i] = cur;
        float* o = pos_s + ((size_t)b * M_ + i) * 3;
        o[0] = q.x; o[1] = q.y; o[2] = q.z;
        if (((i + 1) & 7) == 0)
          __hip_atomic_store(progress + b, i + 1, __ATOMIC_RELEASE,
                             __HIP_MEMORY_SCOPE_AGENT);
      }
    }
    return;
  }

  // ================= persistent worker: kNN + MLP per item =================
  const int w    = tid >> 6;
  const int lane = tid & 63;

  for (;;) {
    if (tid == 0) sh_item = atomicAdd(ctr, 1);
    __syncthreads();
    const int it = sh_item;
    if (it >= NITEM) return;
    const int b    = it & 15;
    const int mset = it >> 4;
    const int m    = mset * 4 + w;

    __syncthreads();   // previous item's LDS reads complete before restage
    {
      const float* pb = pos + (size_t)b * N_ * 3;
      for (int i = tid; i < N_; i += 256)
        sh.f.pp[i] = make_float4(pb[3 * i], pb[3 * i + 1], pb[3 * i + 2], 0.0f);
    }
    if (tid == 0) {
      const int need = (mset + 1) * 4;
      while (__hip_atomic_load(progress + b, __ATOMIC_ACQUIRE,
                               __HIP_MEMORY_SCOPE_AGENT) < need)
        __builtin_amdgcn_s_sleep(16);
    }
    __syncthreads();   // gate passed + staging visible

    int ci0 = 0;
    if (lane == 0)
      ci0 = __hip_atomic_load(fps_idx + b * M_ + m, __ATOMIC_RELAXED,
                              __HIP_MEMORY_SCOPE_AGENT);
    const int ci = __shfl(ci0, 0);
    const float4 c = sh.f.pp[ci];

    // ---- kNN pass A: distances + lane-min key ----
    float d2v[64];
    unsigned long long kmin = ~0ull;
#pragma unroll
    for (int t = 0; t < 64; t++) {
      const int j = t * 64 + lane;
      const float4 p = sh.f.pp[j];
      float dx = __fsub_rn(p.x, c.x);
      float dy = __fsub_rn(p.y, c.y);
      float dz = __fsub_rn(p.z, c.z);
      float d  = __fadd_rn(__fadd_rn(__fmul_rn(dx, dx), __fmul_rn(dy, dy)),
                           __fmul_rn(dz, dz));
      d2v[t] = d;
      const unsigned long long k64 =
          ((unsigned long long)__float_as_uint(d) << 32) | (unsigned int)j;
      if (k64 < kmin) kmin = k64;
    }

    // ---- bitonic sort of lane-min keys; seed top-32; threshold T0 ----
    unsigned long long sk = kmin;
#pragma unroll
    for (int size = 2; size <= 64; size <<= 1) {
#pragma unroll
      for (int stride = size >> 1; stride > 0; stride >>= 1) {
        const unsigned long long other = __shfl_xor(sk, stride);
        const bool up      = ((lane & size) == 0);
        const bool lowhalf = ((lane & stride) == 0);
        const bool takeMin = (up == lowhalf);
        const bool swp     = takeMin ? (other < sk) : (other > sk);
        if (swp) sk = other;
      }
    }
    const unsigned long long T0 = __shfl(sk, 31);
    const bool seeded = (kmin <= T0);

    unsigned long long rkey = (lane < 32) ? sk : ~0ull;
    unsigned long long wk   = T0;

    // ---- pass B: scan, skipping seeded keys ----
#pragma unroll
    for (int t = 0; t < 64; t++) {
      const int j = t * 64 + lane;
      const unsigned long long k64 =
          ((unsigned long long)__float_as_uint(d2v[t]) << 32) | (unsigned int)j;
      const bool skip = seeded && (k64 == kmin);
      unsigned long long mask = __ballot((k64 < wk) && !skip);
      if (mask) {
        while (mask) {
          const int src = __ffsll((unsigned long long)mask) - 1;
          mask &= mask - 1;
          const unsigned long long cand = __shfl(k64, src);
          const int pos_i = (int)__popcll(__ballot(rkey < cand));  // >=32 -> no-op
          const unsigned long long sh_ = __shfl_up(rkey, 1);
          if (lane < 32) {
            if (lane == pos_i)      rkey = cand;
            else if (lane > pos_i)  rkey = sh_;
          }
        }
        wk = __shfl(rkey, 31);
      }
    }
    const int njl = (int)(rkey & 0xFFFFull);   // valid in lanes 0..31
    __syncthreads();   // all pp reads done before mlp buffers alias it

    // ---- gather: wave w fills rows [32w,32w+32) for its centroid ----
    {
      const int rl   = lane >> 1;
      const int half = lane & 1;
      const int r    = w * 32 + rl;
      const int nj   = __shfl(njl, rl);
      const float4* xr = (const float4*)(x + ((size_t)(b * N_ + nj)) * 64 + half * 32);
      __bf16* dst = &sh.g.A[r * AST + half * 32];
#pragma unroll
      for (int t = 0; t < 8; t++) {
        float4 v = xr[t];
        bf16x4 u;
        u[0] = (__bf16)v.x; u[1] = (__bf16)v.y; u[2] = (__bf16)v.z; u[3] = (__bf16)v.w;
        *(bf16x4*)(dst + t * 4) = u;
      }
      bf16x8 z;
#pragma unroll
      for (int q2 = 0; q2 < 8; q2++) z[q2] = (__bf16)0.0f;
      if (half == 0) {
        const float* pj = pos + ((size_t)(b * N_ + nj)) * 3;
        bf16x8 u = z;
        u[0] = (__bf16)(pj[0] - c.x);
        u[1] = (__bf16)(pj[1] - c.y);
        u[2] = (__bf16)(pj[2] - c.z);
        *(bf16x8*)&sh.g.A[r * AST + 64] = u;
        *(bf16x8*)&sh.g.A[r * AST + 72] = z;
      } else {
        *(bf16x8*)&sh.g.A[r * AST + 80] = z;
        *(bf16x8*)&sh.g.A[r * AST + 88] = z;
      }
    }
    __syncthreads();

    const int lrow = lane & 15;
    const int lk8  = (lane >> 4) << 3;
    const int orow = (lane >> 4) << 2;

    // ---- L1: msg(96) @ W1 -> relu -> Bv. Wave w: cols [32w,32w+32) ----
    {
      f32x4 acc[8][2];
#pragma unroll
      for (int n = 0; n < 2; n++) {
        const float bv = b1[(2 * w + n) * 16 + lrow];
        f32x4 a = {bv, bv, bv, bv};
#pragma unroll
        for (int rt = 0; rt < 8; rt++) acc[rt][n] = a;
      }
#pragma unroll
      for (int s = 0; s < 3; s++) {
        bf16x8 a[8];
#pragma unroll
        for (int rt = 0; rt < 8; rt++)
          a[rt] = *(const bf16x8*)&sh.g.A[(rt * 16 + lrow) * AST + s * 32 + lk8];
#pragma unroll
        for (int n = 0; n < 2; n++) {
          bf16x8 bb = *(const bf16x8*)&w1t[((2 * w + n) * 16 + lrow) * 96 + s * 32 + lk8];
#pragma unroll
          for (int rt = 0; rt < 8; rt++)
            acc[rt][n] = __builtin_amdgcn_mfma_f32_16x16x32_bf16(a[rt], bb, acc[rt][n], 0, 0, 0);
        }
      }
      __syncthreads();
#pragma unroll
      for (int n = 0; n < 2; n++)
#pragma unroll
        for (int rt = 0; rt < 8; rt++)
#pragma unroll
          for (int j = 0; j < 4; j++)
            sh.g.Bv[(rt * 16 + orow + j) * AST + (2 * w + n) * 16 + lrow] =
                (__bf16)fmaxf(acc[rt][n][j], 0.0f);
    }
    __syncthreads();

    // ---- L2: Bv(128) @ W2 -> relu -> A ----
    {
      f32x4 acc[8][2];
#pragma unroll
      for (int n = 0; n < 2; n++) {
        const float bv = b2[(2 * w + n) * 16 + lrow];
        f32x4 a = {bv, bv, bv, bv};
#pragma unroll
        for (int rt = 0; rt < 8; rt++) acc[rt][n] = a;
      }
#pragma unroll
      for (int s = 0; s < 4; s++) {
        bf16x8 a[8];
#pragma unroll
        for (int rt = 0; rt < 8; rt++)
          a[rt] = *(const bf16x8*)&sh.g.Bv[(rt * 16 + lrow) * AST + s * 32 + lk8];
#pragma unroll
        for (int n = 0; n < 2; n++) {
          bf16x8 bb = *(const bf16x8*)&w2t[((2 * w + n) * 16 + lrow) * 128 + s * 32 + lk8];
#pragma unroll
          for (int rt = 0; rt < 8; rt++)
            acc[rt][n] = __builtin_amdgcn_mfma_f32_16x16x32_bf16(a[rt], bb, acc[rt][n], 0, 0, 0);
        }
      }
      __syncthreads();
#pragma unroll
      for (int n = 0; n < 2; n++)
#pragma unroll
        for (int rt = 0; rt < 8; rt++)
#pragma unroll
          for (int j = 0; j < 4; j++)
            sh.g.A[(rt * 16 + orow + j) * AST + (2 * w + n) * 16 + lrow] =
                (__bf16)fmaxf(acc[rt][n][j], 0.0f);
    }
    __syncthreads();

    // ---- L3 + maxpool. Wave w: cols [64w,64w+64) in two passes ----
#pragma unroll
    for (int np = 0; np < 2; np++) {
      f32x4 acc[8][2];
#pragma unroll
      for (int n = 0; n < 2; n++) {
        const float bv = b3[(4 * w + 2 * np + n) * 16 + lrow];
        f32x4 a = {bv, bv, bv, bv};
#pragma unroll
        for (int rt = 0; rt < 8; rt++) acc[rt][n] = a;
      }
#pragma unroll
      for (int s = 0; s < 4; s++) {
        bf16x8 a[8];
#pragma unroll
        for (int rt = 0; rt < 8; rt++)
          a[rt] = *(const bf16x8*)&sh.g.A[(rt * 16 + lrow) * AST + s * 32 + lk8];
#pragma unroll
        for (int n = 0; n < 2; n++) {
          bf16x8 bb = *(const bf16x8*)&w3t[((4 * w + 2 * np + n) * 16 + lrow) * 128 + s * 32 + lk8];
#pragma unroll
          for (int rt = 0; rt < 8; rt++)
            acc[rt][n] = __builtin_amdgcn_mfma_f32_16x16x32_bf16(a[rt], bb, acc[rt][n], 0, 0, 0);
        }
      }
#pragma unroll
      for (int ccc = 0; ccc < 4; ccc++) {
#pragma unroll
        for (int n = 0; n < 2; n++) {
          f32x4 a0 = acc[2 * ccc][n], a1 = acc[2 * ccc + 1][n];
          float v = fmaxf(fmaxf(fmaxf(a0[0], a0[1]), fmaxf(a0[2], a0[3])),
                          fmaxf(fmaxf(a1[0], a1[1]), fmaxf(a1[2], a1[3])));
          v = fmaxf(v, __shfl_xor(v, 16));
          v = fmaxf(v, __shfl_xor(v, 32));
          v = fmaxf(v, 0.0f);
          if (lane < 16)
            out[((size_t)(b * M_ + mset * 4 + ccc)) * 256 + (4 * w + 2 * np + n) * 16 + lane] = v;
        }
      }
    }
    // loop to next item
  }
}

// ---------------------------------------------------------------------------
extern "C" void kernel_launch(void* const* d_in, const int* in_sizes, int n_in,
                              void* d_out, int out_size, void* d_ws, size_t ws_size,
                              hipStream_t stream) {
  const float* x   = (const float*)d_in[0];
  const float* pos = (const float*)d_in[1];
  const float* W1  = (const float*)d_in[2];
  const float* b1  = (const float*)d_in[3];
  const float* W2  = (const float*)d_in[4];
  const float* b2  = (const float*)d_in[5];
  const float* W3  = (const float*)d_in[6];
  const float* b3  = (const float*)d_in[7];

  float* out   = (float*)d_out;
  float* pos_s = out + (size_t)B_ * M_ * 256;

  char* ws = (char*)d_ws;
  int*    fps_idx  = (int*)ws;                       // 65536 B
  int*    progress = (int*)(ws + 65536);             // 64 B
  int*    ctr      = (int*)(ws + 65600);             // 4 B
  __bf16* w1t      = (__bf16*)(ws + 65792);          // 24576 B
  __bf16* w2t      = (__bf16*)(ws + 90368);          // 32768 B
  __bf16* w3t      = (__bf16*)(ws + 123136);         // 65536 B

  hipMemsetAsync(ws + 65536, 0, 68, stream);         // progress[16] + ctr
  prep_weights<<<dim3(128), dim3(256), 0, stream>>>(W1, W2, W3, w1t, w2t, w3t);
  fused_kernel<<<dim3(B_ + NWORK), dim3(256), 0, stream>>>(
      pos, x, b1, b2, b3, w1t, w2t, w3t, fps_idx, progress, ctr, out, pos_s);
}

// Round 8
// 666.519 us; speedup vs baseline: 2.5101x; 1.2072x over previous
//
#include <hip/hip_runtime.h>

// SAModule (PointNet++): FPS -> kNN(32) -> [x||rel] MLP(67->128->128->256) -> max over K.
// B=16, N=4096, C=64, M=1024, K=32.
// R7: fence-free producer/consumer. FPS publishes each index as a RELAXED
// agent atomic store of (idx+1) into ipub[b*M+i] (datum == flag; no release
// -> no buffer_wbl2 L2-writeback each publish). Worker waves poll their own
// ipub word with RELAXED agent atomic loads (no acquire -> no buffer_inv
// cache-thrash). R5/R6's release/acquire fences cost FPS ~185us.

#define B_    16
#define N_    4096
#define M_    1024
#define AST   136
#define NWORK 240
#define NITEM (256 * 16)   // items ordered mset-major: it = mset*16 + b

typedef __bf16 bf16x8 __attribute__((ext_vector_type(8)));
typedef __bf16 bf16x4 __attribute__((ext_vector_type(4)));
typedef float  f32x4  __attribute__((ext_vector_type(4)));
typedef float  f32x2  __attribute__((ext_vector_type(2)));

// ---------------------------------------------------------------------------
// Weight prep: transpose + cast to bf16, pad W1 K-dim 67->96 with zeros.
// ---------------------------------------------------------------------------
__global__ __launch_bounds__(256) void prep_weights(
    const float* __restrict__ W1, const float* __restrict__ W2,
    const float* __restrict__ W3,
    __bf16* __restrict__ w1t, __bf16* __restrict__ w2t, __bf16* __restrict__ w3t) {
  const int t = blockIdx.x * 256 + threadIdx.x;   // 0..32767
  if (t < 128 * 96) {
    const int n = t / 96, k = t % 96;
    w1t[t] = (k < 67) ? (__bf16)W1[k * 128 + n] : (__bf16)0.0f;
  }
  if (t < 128 * 128) {
    const int n = t >> 7, k = t & 127;
    w2t[t] = (__bf16)W2[k * 128 + n];
  }
  {
    const int n = t >> 7, k = t & 127;   // t < 256*128 always
    w3t[t] = (__bf16)W3[k * 256 + n];
  }
}

// ---------------------------------------------------------------------------
__device__ __forceinline__ f32x2 pk_sub(f32x2 a, f32x2 b) {
  f32x2 d;
  asm("v_pk_add_f32 %0, %1, %2 neg_lo:[0,1] neg_hi:[0,1]" : "=v"(d) : "v"(a), "v"(b));
  return d;
}
__device__ __forceinline__ f32x2 pk_mul(f32x2 a, f32x2 b) {
  f32x2 d;
  asm("v_pk_mul_f32 %0, %1, %2" : "=v"(d) : "v"(a), "v"(b));
  return d;
}
__device__ __forceinline__ f32x2 pk_add(f32x2 a, f32x2 b) {
  f32x2 d;
  asm("v_pk_add_f32 %0, %1, %2" : "=v"(d) : "v"(a), "v"(b));
  return d;
}

template <int CTRL>
__device__ __forceinline__ unsigned long long dpp_max_u64(unsigned long long k) {
  unsigned lo = (unsigned)__builtin_amdgcn_update_dpp(0, (int)(unsigned)k,         CTRL, 0xF, 0xF, true);
  unsigned hi = (unsigned)__builtin_amdgcn_update_dpp(0, (int)(unsigned)(k >> 32), CTRL, 0xF, 0xF, true);
  unsigned long long p = ((unsigned long long)hi << 32) | lo;
  return p > k ? p : k;
}

union ShU {
  struct { float4 pp[N_]; unsigned long long sw[2][4]; } f;   // fps / knn view
  struct { __bf16 A[128 * AST]; __bf16 Bv[128 * AST]; } g;    // mlp view
};

// ---------------------------------------------------------------------------
__global__ __launch_bounds__(256) void fused_kernel(
    const float* __restrict__ pos, const float* __restrict__ x,
    const float* __restrict__ b1, const float* __restrict__ b2,
    const float* __restrict__ b3,
    const __bf16* __restrict__ w1t, const __bf16* __restrict__ w2t,
    const __bf16* __restrict__ w3t,
    int* __restrict__ ipub, int* __restrict__ ctr,
    float* __restrict__ out, float* __restrict__ pos_s) {
  __shared__ alignas(16) ShU sh;
  __shared__ int sh_item;
  const int tid = threadIdx.x;

  if (blockIdx.x < B_) {
    // ================= FPS producer (R4's verified 638us body) =================
    __builtin_amdgcn_s_setprio(3);
    const int b = blockIdx.x;
    const float* pb = pos + (size_t)b * N_ * 3;
    for (int i = tid; i < N_; i += 256)
      sh.f.pp[i] = make_float4(pb[3 * i], pb[3 * i + 1], pb[3 * i + 2], 0.0f);
    __syncthreads();

    f32x2 X2[8], Y2[8], Z2[8];
    float D[16];
    unsigned lo16[16];
    const unsigned ntid = ~(unsigned)tid;
#pragma unroll
    for (int j = 0; j < 8; j++) {
      float4 p0 = sh.f.pp[tid + ((2 * j) << 8)];
      float4 p1 = sh.f.pp[tid + ((2 * j + 1) << 8)];
      X2[j][0] = p0.x; X2[j][1] = p1.x;
      Y2[j][0] = p0.y; Y2[j][1] = p1.y;
      Z2[j][0] = p0.z; Z2[j][1] = p1.z;
      D[2 * j] = 1e30f; D[2 * j + 1] = 1e30f;
      lo16[2 * j]     = ntid - (unsigned)((2 * j) << 8);
      lo16[2 * j + 1] = ntid - (unsigned)((2 * j + 1) << 8);
    }

    float4 q = sh.f.pp[0];
    if (tid == 0) {
      __hip_atomic_store(ipub + b * M_, 1, __ATOMIC_RELAXED,
                         __HIP_MEMORY_SCOPE_AGENT);   // idx 0, published as 0+1
      float* o = pos_s + (size_t)b * M_ * 3;
      o[0] = q.x; o[1] = q.y; o[2] = q.z;
    }

    for (int i = 1; i < M_; i++) {
      f32x2 qx; qx[0] = q.x; qx[1] = q.x;
      f32x2 qy; qy[0] = q.y; qy[1] = q.y;
      f32x2 qz; qz[0] = q.z; qz[1] = q.z;
      unsigned long long key[16];
#pragma unroll
      for (int j = 0; j < 8; j++) {
        f32x2 dx = pk_sub(X2[j], qx);
        f32x2 dy = pk_sub(Y2[j], qy);
        f32x2 dz = pk_sub(Z2[j], qz);
        f32x2 t0 = pk_mul(dx, dx);
        f32x2 t1 = pk_mul(dy, dy);
        f32x2 s  = pk_add(t0, t1);
        f32x2 t2 = pk_mul(dz, dz);
        f32x2 d2 = pk_add(s, t2);
        D[2 * j]     = fminf(D[2 * j],     d2[0]);
        D[2 * j + 1] = fminf(D[2 * j + 1], d2[1]);
        key[2 * j]     = ((unsigned long long)__float_as_uint(D[2 * j])     << 32) | lo16[2 * j];
        key[2 * j + 1] = ((unsigned long long)__float_as_uint(D[2 * j + 1]) << 32) | lo16[2 * j + 1];
      }
#pragma unroll
      for (int s = 8; s > 0; s >>= 1)
#pragma unroll
        for (int k = 0; k < s; k++)
          if (key[k + s] > key[k]) key[k] = key[k + s];
      unsigned long long kk = key[0];

      kk = dpp_max_u64<0xB1>(kk);    // quad_perm xor1
      kk = dpp_max_u64<0x4E>(kk);    // quad_perm xor2
      kk = dpp_max_u64<0x141>(kk);   // row_half_mirror (xor4)
      kk = dpp_max_u64<0x140>(kk);   // row_mirror (xor8)
      kk = dpp_max_u64<0x142>(kk);   // row_bcast15
      kk = dpp_max_u64<0x143>(kk);   // row_bcast31

      const int par = i & 1;
      if ((tid & 63) == 63) sh.f.sw[par][tid >> 6] = kk;
      __syncthreads();

      const ulonglong2 v01 = *(const ulonglong2*)&sh.f.sw[par][0];
      const ulonglong2 v23 = *(const ulonglong2*)&sh.f.sw[par][2];
      const int c0 = (int)(~(unsigned)v01.x), c1 = (int)(~(unsigned)v01.y);
      const int c2 = (int)(~(unsigned)v23.x), c3 = (int)(~(unsigned)v23.y);
      float4 q0 = sh.f.pp[c0], q1 = sh.f.pp[c1], q2 = sh.f.pp[c2], q3 = sh.f.pp[c3];
      unsigned long long k01, k23; float4 q01, q23; int i01, i23;
      if (v01.y > v01.x) { k01 = v01.y; q01 = q1; i01 = c1; }
      else               { k01 = v01.x; q01 = q0; i01 = c0; }
      if (v23.y > v23.x) { k23 = v23.y; q23 = q3; i23 = c3; }
      else               { k23 = v23.x; q23 = q2; i23 = c2; }
      int cur;
      if (k23 > k01) { q = q23; cur = i23; }
      else           { q = q01; cur = i01; }

      if (tid == 0) {
        __hip_atomic_store(ipub + b * M_ + i, cur + 1, __ATOMIC_RELAXED,
                           __HIP_MEMORY_SCOPE_AGENT);   // datum == flag
        float* o = pos_s + ((size_t)b * M_ + i) * 3;
        o[0] = q.x; o[1] = q.y; o[2] = q.z;
      }
    }
    return;
  }

  // ================= persistent worker: kNN + MLP per item =================
  const int w    = tid >> 6;
  const int lane = tid & 63;

  for (;;) {
    if (tid == 0) sh_item = atomicAdd(ctr, 1);
    __syncthreads();
    const int it = sh_item;
    if (it >= NITEM) return;
    const int b    = it & 15;
    const int mset = it >> 4;
    const int m    = mset * 4 + w;

    __syncthreads();   // previous item's LDS reads complete before restage
    {
      const float* pb = pos + (size_t)b * N_ * 3;
      for (int i = tid; i < N_; i += 256)
        sh.f.pp[i] = make_float4(pb[3 * i], pb[3 * i + 1], pb[3 * i + 2], 0.0f);
    }
    __syncthreads();   // staging visible to all waves

    // per-wave poll of its own published index (relaxed agent load; the
    // word itself is the ready-flag, so no acquire fence is needed)
    int ci0 = 0;
    if (lane == 0) {
      int v;
      while ((v = __hip_atomic_load(ipub + b * M_ + m, __ATOMIC_RELAXED,
                                    __HIP_MEMORY_SCOPE_AGENT)) == 0)
        __builtin_amdgcn_s_sleep(8);
      ci0 = v - 1;
    }
    const int ci = __shfl(ci0, 0);
    const float4 c = sh.f.pp[ci];

    // ---- kNN pass A: distances + lane-min key ----
    float d2v[64];
    unsigned long long kmin = ~0ull;
#pragma unroll
    for (int t = 0; t < 64; t++) {
      const int j = t * 64 + lane;
      const float4 p = sh.f.pp[j];
      float dx = __fsub_rn(p.x, c.x);
      float dy = __fsub_rn(p.y, c.y);
      float dz = __fsub_rn(p.z, c.z);
      float d  = __fadd_rn(__fadd_rn(__fmul_rn(dx, dx), __fmul_rn(dy, dy)),
                           __fmul_rn(dz, dz));
      d2v[t] = d;
      const unsigned long long k64 =
          ((unsigned long long)__float_as_uint(d) << 32) | (unsigned int)j;
      if (k64 < kmin) kmin = k64;
    }

    // ---- bitonic sort of lane-min keys; seed top-32; threshold T0 ----
    unsigned long long sk = kmin;
#pragma unroll
    for (int size = 2; size <= 64; size <<= 1) {
#pragma unroll
      for (int stride = size >> 1; stride > 0; stride >>= 1) {
        const unsigned long long other = __shfl_xor(sk, stride);
        const bool up      = ((lane & size) == 0);
        const bool lowhalf = ((lane & stride) == 0);
        const bool takeMin = (up == lowhalf);
        const bool swp     = takeMin ? (other < sk) : (other > sk);
        if (swp) sk = other;
      }
    }
    const unsigned long long T0 = __shfl(sk, 31);
    const bool seeded = (kmin <= T0);

    unsigned long long rkey = (lane < 32) ? sk : ~0ull;
    unsigned long long wk   = T0;

    // ---- pass B: scan, skipping seeded keys ----
#pragma unroll
    for (int t = 0; t < 64; t++) {
      const int j = t * 64 + lane;
      const unsigned long long k64 =
          ((unsigned long long)__float_as_uint(d2v[t]) << 32) | (unsigned int)j;
      const bool skip = seeded && (k64 == kmin);
      unsigned long long mask = __ballot((k64 < wk) && !skip);
      if (mask) {
        while (mask) {
          const int src = __ffsll((unsigned long long)mask) - 1;
          mask &= mask - 1;
          const unsigned long long cand = __shfl(k64, src);
          const int pos_i = (int)__popcll(__ballot(rkey < cand));  // >=32 -> no-op
          const unsigned long long sh_ = __shfl_up(rkey, 1);
          if (lane < 32) {
            if (lane == pos_i)      rkey = cand;
            else if (lane > pos_i)  rkey = sh_;
          }
        }
        wk = __shfl(rkey, 31);
      }
    }
    const int njl = (int)(rkey & 0xFFFFull);   // valid in lanes 0..31
    __syncthreads();   // all pp reads done before mlp buffers alias it

    // ---- gather: wave w fills rows [32w,32w+32) for its centroid ----
    {
      const int rl   = lane >> 1;
      const int half = lane & 1;
      const int r    = w * 32 + rl;
      const int nj   = __shfl(njl, rl);
      const float4* xr = (const float4*)(x + ((size_t)(b * N_ + nj)) * 64 + half * 32);
      __bf16* dst = &sh.g.A[r * AST + half * 32];
#pragma unroll
      for (int t = 0; t < 8; t++) {
        float4 v = xr[t];
        bf16x4 u;
        u[0] = (__bf16)v.x; u[1] = (__bf16)v.y; u[2] = (__bf16)v.z; u[3] = (__bf16)v.w;
        *(bf16x4*)(dst + t * 4) = u;
      }
      bf16x8 z;
#pragma unroll
      for (int q2 = 0; q2 < 8; q2++) z[q2] = (__bf16)0.0f;
      if (half == 0) {
        const float* pj = pos + ((size_t)(b * N_ + nj)) * 3;
        bf16x8 u = z;
        u[0] = (__bf16)(pj[0] - c.x);
        u[1] = (__bf16)(pj[1] - c.y);
        u[2] = (__bf16)(pj[2] - c.z);
        *(bf16x8*)&sh.g.A[r * AST + 64] = u;
        *(bf16x8*)&sh.g.A[r * AST + 72] = z;
      } else {
        *(bf16x8*)&sh.g.A[r * AST + 80] = z;
        *(bf16x8*)&sh.g.A[r * AST + 88] = z;
      }
    }
    __syncthreads();

    const int lrow = lane & 15;
    const int lk8  = (lane >> 4) << 3;
    const int orow = (lane >> 4) << 2;

    // ---- L1: msg(96) @ W1 -> relu -> Bv. Wave w: cols [32w,32w+32) ----
    {
      f32x4 acc[8][2];
#pragma unroll
      for (int n = 0; n < 2; n++) {
        const float bv = b1[(2 * w + n) * 16 + lrow];
        f32x4 a = {bv, bv, bv, bv};
#pragma unroll
        for (int rt = 0; rt < 8; rt++) acc[rt][n] = a;
      }
#pragma unroll
      for (int s = 0; s < 3; s++) {
        bf16x8 a[8];
#pragma unroll
        for (int rt = 0; rt < 8; rt++)
          a[rt] = *(const bf16x8*)&sh.g.A[(rt * 16 + lrow) * AST + s * 32 + lk8];
#pragma unroll
        for (int n = 0; n < 2; n++) {
          bf16x8 bb = *(const bf16x8*)&w1t[((2 * w + n) * 16 + lrow) * 96 + s * 32 + lk8];
#pragma unroll
          for (int rt = 0; rt < 8; rt++)
            acc[rt][n] = __builtin_amdgcn_mfma_f32_16x16x32_bf16(a[rt], bb, acc[rt][n], 0, 0, 0);
        }
      }
      __syncthreads();
#pragma unroll
      for (int n = 0; n < 2; n++)
#pragma unroll
        for (int rt = 0; rt < 8; rt++)
#pragma unroll
          for (int j = 0; j < 4; j++)
            sh.g.Bv[(rt * 16 + orow + j) * AST + (2 * w + n) * 16 + lrow] =
                (__bf16)fmaxf(acc[rt][n][j], 0.0f);
    }
    __syncthreads();

    // ---- L2: Bv(128) @ W2 -> relu -> A ----
    {
      f32x4 acc[8][2];
#pragma unroll
      for (int n = 0; n < 2; n++) {
        const float bv = b2[(2 * w + n) * 16 + lrow];
        f32x4 a = {bv, bv, bv, bv};
#pragma unroll
        for (int rt = 0; rt < 8; rt++) acc[rt][n] = a;
      }
#pragma unroll
      for (int s = 0; s < 4; s++) {
        bf16x8 a[8];
#pragma unroll
        for (int rt = 0; rt < 8; rt++)
          a[rt] = *(const bf16x8*)&sh.g.Bv[(rt * 16 + lrow) * AST + s * 32 + lk8];
#pragma unroll
        for (int n = 0; n < 2; n++) {
          bf16x8 bb = *(const bf16x8*)&w2t[((2 * w + n) * 16 + lrow) * 128 + s * 32 + lk8];
#pragma unroll
          for (int rt = 0; rt < 8; rt++)
            acc[rt][n] = __builtin_amdgcn_mfma_f32_16x16x32_bf16(a[rt], bb, acc[rt][n], 0, 0, 0);
        }
      }
      __syncthreads();
#pragma unroll
      for (int n = 0; n < 2; n++)
#pragma unroll
        for (int rt = 0; rt < 8; rt++)
#pragma unroll
          for (int j = 0; j < 4; j++)
            sh.g.A[(rt * 16 + orow + j) * AST + (2 * w + n) * 16 + lrow] =
                (__bf16)fmaxf(acc[rt][n][j], 0.0f);
    }
    __syncthreads();

    // ---- L3 + maxpool. Wave w: cols [64w,64w+64) in two passes ----
#pragma unroll
    for (int np = 0; np < 2; np++) {
      f32x4 acc[8][2];
#pragma unroll
      for (int n = 0; n < 2; n++) {
        const float bv = b3[(4 * w + 2 * np + n) * 16 + lrow];
        f32x4 a = {bv, bv, bv, bv};
#pragma unroll
        for (int rt = 0; rt < 8; rt++) acc[rt][n] = a;
      }
#pragma unroll
      for (int s = 0; s < 4; s++) {
        bf16x8 a[8];
#pragma unroll
        for (int rt = 0; rt < 8; rt++)
          a[rt] = *(const bf16x8*)&sh.g.A[(rt * 16 + lrow) * AST + s * 32 + lk8];
#pragma unroll
        for (int n = 0; n < 2; n++) {
          bf16x8 bb = *(const bf16x8*)&w3t[((4 * w + 2 * np + n) * 16 + lrow) * 128 + s * 32 + lk8];
#pragma unroll
          for (int rt = 0; rt < 8; rt++)
            acc[rt][n] = __builtin_amdgcn_mfma_f32_16x16x32_bf16(a[rt], bb, acc[rt][n], 0, 0, 0);
        }
      }
#pragma unroll
      for (int ccc = 0; ccc < 4; ccc++) {
#pragma unroll
        for (int n = 0; n < 2; n++) {
          f32x4 a0 = acc[2 * ccc][n], a1 = acc[2 * ccc + 1][n];
          float v = fmaxf(fmaxf(fmaxf(a0[0], a0[1]), fmaxf(a0[2], a0[3])),
                          fmaxf(fmaxf(a1[0], a1[1]), fmaxf(a1[2], a1[3])));
          v = fmaxf(v, __shfl_xor(v, 16));
          v = fmaxf(v, __shfl_xor(v, 32));
          v = fmaxf(v, 0.0f);
          if (lane < 16)
            out[((size_t)(b * M_ + mset * 4 + ccc)) * 256 + (4 * w + 2 * np + n) * 16 + lane] = v;
        }
      }
    }
    // loop to next item
  }
}

// ---------------------------------------------------------------------------
extern "C" void kernel_launch(void* const* d_in, const int* in_sizes, int n_in,
                              void* d_out, int out_size, void* d_ws, size_t ws_size,
                              hipStream_t stream) {
  const float* x   = (const float*)d_in[0];
  const float* pos = (const float*)d_in[1];
  const float* W1  = (const float*)d_in[2];
  const float* b1  = (const float*)d_in[3];
  const float* W2  = (const float*)d_in[4];
  const float* b2  = (const float*)d_in[5];
  const float* W3  = (const float*)d_in[6];
  const float* b3  = (const float*)d_in[7];

  float* out   = (float*)d_out;
  float* pos_s = out + (size_t)B_ * M_ * 256;

  char* ws = (char*)d_ws;
  int*    ipub = (int*)ws;                        // 65536 B: published idx+1
  int*    ctr  = (int*)(ws + 65536);              // 4 B
  __bf16* w1t  = (__bf16*)(ws + 65792);           // 24576 B
  __bf16* w2t  = (__bf16*)(ws + 90368);           // 32768 B
  __bf16* w3t  = (__bf16*)(ws + 123136);          // 65536 B

  hipMemsetAsync(ws, 0, 65540, stream);           // ipub + ctr
  prep_weights<<<dim3(128), dim3(256), 0, stream>>>(W1, W2, W3, w1t, w2t, w3t);
  fused_kernel<<<dim3(B_ + NWORK), dim3(256), 0, stream>>>(
      pos, x, b1, b2, b3, w1t, w2t, w3t, ipub, ctr, out, pos_s);
}